// Round 6
// baseline (262.814 us; speedup 1.0000x reference)
//
#include <hip/hip_runtime.h>
#include <hip/hip_bf16.h>

// Problem constants
#define B_    2
#define S_    1024
#define HID_  1024
#define H_    16
#define P_    2
#define D_    64
#define SV_   2048   // S_*P_
#define NBH_  32     // B_*H_
// SCALE * log2(e) = 0.125 * 1.4426950408889634
#define SCALE_LOG2E 0.18033688f

typedef __attribute__((ext_vector_type(8))) short short8;
typedef __attribute__((ext_vector_type(4))) short short4b;
typedef __attribute__((ext_vector_type(4))) float f32x4;

#if __has_builtin(__builtin_amdgcn_exp2f)
#define EXP2(x) __builtin_amdgcn_exp2f(x)
#else
#define EXP2(x) exp2f(x)
#endif

__device__ __forceinline__ unsigned short f2bf(float f) {
  union { float f; unsigned u; } v; v.f = f;
  unsigned r = v.u + 0x7fffu + ((v.u >> 16) & 1u);
  return (unsigned short)(r >> 16);
}
__device__ __forceinline__ unsigned pack_bf2(float a, float b) {
  __hip_bfloat162 h = __float22bfloat162_rn(make_float2(a, b));
  unsigned u; __builtin_memcpy(&u, &h, 4);
  return u;
}

// ---------------------------------------------------------------------------
__global__ __launch_bounds__(256) void cast_f32_bf16(
    const float* __restrict__ src, unsigned short* __restrict__ dst, int n4) {
  int i = blockIdx.x * blockDim.x + threadIdx.x;
  int stride = gridDim.x * blockDim.x;
  for (; i < n4; i += stride) {
    float4 v = ((const float4*)src)[i];
    ushort4 o;
    o.x = f2bf(v.x); o.y = f2bf(v.y); o.z = f2bf(v.z); o.w = f2bf(v.w);
    ((ushort4*)dst)[i] = o;
  }
}

// ---------------------------------------------------------------------------
// Weff[t][r=(h*128+p*64+d)][e] = sum_m A[m*32+hp] * W[m*64+d][e]
__global__ __launch_bounds__(256) void weff_kernel(
    const float* __restrict__ Wq, const float* __restrict__ Wk,
    const float* __restrict__ Wv,
    const float* __restrict__ aq, const float* __restrict__ ak,
    const float* __restrict__ av,
    unsigned short* __restrict__ Weff) {
  __shared__ float Al[16][32];
  const int d = blockIdx.x;   // 0..63
  const int t = blockIdx.y;   // 0..2
  const float* W = (t == 0) ? Wq : ((t == 1) ? Wk : Wv);
  const float* A = (t == 0) ? aq : ((t == 1) ? ak : av);
  const int tid = threadIdx.x;
  for (int idx = tid; idx < 512; idx += 256) Al[idx >> 5][idx & 31] = A[idx];
  __syncthreads();
  const int e = tid * 4;
  float wr[16][4];
#pragma unroll
  for (int m = 0; m < 16; ++m) {
    float4 v = *(const float4*)(W + (size_t)(m * 64 + d) * 1024 + e);
    wr[m][0] = v.x; wr[m][1] = v.y; wr[m][2] = v.z; wr[m][3] = v.w;
  }
  for (int hp = 0; hp < 32; ++hp) {
    float acc0 = 0.f, acc1 = 0.f, acc2 = 0.f, acc3 = 0.f;
#pragma unroll
    for (int m = 0; m < 16; ++m) {
      float al = Al[m][hp];
      acc0 += al * wr[m][0]; acc1 += al * wr[m][1];
      acc2 += al * wr[m][2]; acc3 += al * wr[m][3];
    }
    int r = (hp >> 1) * 128 + (hp & 1) * 64 + d;
    ushort4 ov;
    ov.x = f2bf(acc0); ov.y = f2bf(acc1); ov.z = f2bf(acc2); ov.w = f2bf(acc3);
    *(ushort4*)(Weff + ((size_t)t * 2048 + r) * 1024 + e) = ov;
  }
}

// ---------------------------------------------------------------------------
// Woeff[f][o*64+d] = sum_h coll[h*32+o] * Wo[f][h*64+d]   (bf16 out)
__global__ __launch_bounds__(256) void woeff_kernel(
    const float* __restrict__ Wo, const float* __restrict__ coll,
    unsigned short* __restrict__ Woeff) {
  __shared__ float wrow[1024];
  __shared__ float cl[512];
  const int f = blockIdx.x;
  const int tid = threadIdx.x;
  for (int idx = tid; idx < 512; idx += 256) cl[idx] = coll[idx];
  for (int idx = tid; idx < 1024; idx += 256) wrow[idx] = Wo[(size_t)f * 1024 + idx];
  __syncthreads();
  for (int idx = tid; idx < 2048; idx += 256) {
    int o = idx >> 6, d = idx & 63;
    float acc = 0.f;
#pragma unroll
    for (int h = 0; h < 16; ++h) acc += wrow[h * 64 + d] * cl[h * 32 + o];
    Woeff[(size_t)f * 2048 + idx] = f2bf(acc);
  }
}

// ---------------------------------------------------------------------------
// Unified QKV GEMM — 256x256-tile 8-phase schedule, DEPTH-2.5 PIPELINE.
// BM=BN=256, BK=64, 8 waves (2M x 4N), 512 threads, LDS 160 KiB:
// A TRIPLE-buffered, B double-buffered (phase-2/3 overwrite trick).
// Per-tile wait vmcnt(8) drains only loads issued TWO tiles back.
// Q output (z==0) PRE-SCALED by SCALE_LOG2E for exp2-direct attn.
__global__ __launch_bounds__(512) void qkv_gemm256(
    const unsigned short* __restrict__ Xb,
    const unsigned short* __restrict__ Weff,
    unsigned short* __restrict__ Qd, unsigned short* __restrict__ Kd,
    unsigned short* __restrict__ Vd) {
  __shared__ unsigned short As[3][256 * 64];   // 96 KiB
  __shared__ unsigned short Bs[2][256 * 64];   // 64 KiB  -> 160 KiB total
  constexpr int K = 1024;
  constexpr int NT = 16;                        // K / 64
  const int t = threadIdx.x;
  const int wave = t >> 6, lane = t & 63, lrow = lane & 15, quad = lane >> 4;
  const int wm = wave >> 2, wn = wave & 3;      // 2M x 4N wave grid
  const int z = blockIdx.z;
  const int row0 = blockIdx.x * 256, col0 = blockIdx.y * 256;
  const unsigned short* Ap = (z == 2) ? (Weff + (size_t)2 * 2048 * 1024) : Xb;
  const unsigned short* Bp = (z == 2) ? Xb : (Weff + (size_t)z * 2048 * 1024);

  const int srow8 = lane >> 3;                 // row within the 8-row chunk
  const int sslot = (lane & 7) ^ srow8;        // pre-swizzled global 16B slot

  auto stageHT = [&](const unsigned short* __restrict__ gsrc,
                     unsigned short* __restrict__ ldsbase,
                     int half, int kt, int trow0) {
#pragma unroll
    for (int j = 0; j < 2; ++j) {
      const int rloc = half * 128 + wave * 16 + j * 8;  // wave-uniform
      const unsigned short* g =
          gsrc + (size_t)(trow0 + rloc + srow8) * K + kt * 64 + sslot * 8;
      __builtin_amdgcn_global_load_lds(
          (const __attribute__((address_space(1))) unsigned int*)g,
          (__attribute__((address_space(3))) unsigned int*)(ldsbase + rloc * 64),
          16, 0, 0);
    }
  };

  f32x4 acc[8][4];
#pragma unroll
  for (int mi = 0; mi < 8; ++mi)
#pragma unroll
    for (int ni = 0; ni < 4; ++ni) acc[mi][ni] = (f32x4){0.f, 0.f, 0.f, 0.f};

  stageHT(Ap, &As[0][0], 0, 0, row0);
  stageHT(Ap, &As[0][0], 1, 0, row0);
  stageHT(Bp, &Bs[0][0], 0, 0, col0);
  stageHT(Bp, &Bs[0][0], 1, 0, col0);
  stageHT(Ap, &As[1][0], 0, 1, row0);
  stageHT(Ap, &As[1][0], 1, 1, row0);
  stageHT(Bp, &Bs[1][0], 0, 1, col0);
  stageHT(Bp, &Bs[1][0], 1, 1, col0);
  asm volatile("s_waitcnt vmcnt(8)" ::: "memory");
  asm volatile("s_barrier" ::: "memory");

  const int swz = lrow & 7;

#define LDA(mi, ks)                                                         \
  (*(const short8*)(Ab + (wm * 128 + (mi)*16 + lrow) * 64 +                 \
                    ((((ks)*4 + quad) ^ swz) * 8)))

#define MFMA_PAIR(mA, mB, a00, a01, a10, a11)                               \
  _Pragma("unroll") for (int ni = 0; ni < 4; ++ni) {                        \
    acc[mA][ni] = __builtin_amdgcn_mfma_f32_16x16x32_bf16(                  \
        a00, bfrag[ni][0], acc[mA][ni], 0, 0, 0);                           \
    acc[mA][ni] = __builtin_amdgcn_mfma_f32_16x16x32_bf16(                  \
        a01, bfrag[ni][1], acc[mA][ni], 0, 0, 0);                           \
    acc[mB][ni] = __builtin_amdgcn_mfma_f32_16x16x32_bf16(                  \
        a10, bfrag[ni][0], acc[mB][ni], 0, 0, 0);                           \
    acc[mB][ni] = __builtin_amdgcn_mfma_f32_16x16x32_bf16(                  \
        a11, bfrag[ni][1], acc[mB][ni], 0, 0, 0);                           \
  }

  for (int kt = 0; kt < NT; ++kt) {
    const int abuf = kt % 3;
    const int anext = (kt + 2) % 3;
    const int bbuf = kt & 1;
    const bool pf = (kt + 2 < NT);
    const unsigned short* __restrict__ Ab = &As[abuf][0];
    const unsigned short* __restrict__ Bb = &Bs[bbuf][0];

    short8 bfrag[4][2];
    {
#pragma unroll
      for (int ni = 0; ni < 4; ++ni) {
        const int R = wn * 64 + ni * 16 + lrow;
#pragma unroll
        for (int ks = 0; ks < 2; ++ks)
          bfrag[ni][ks] =
              *(const short8*)(Bb + R * 64 + (((ks * 4 + quad) ^ swz) * 8));
      }
      short8 a00 = LDA(0, 0), a01 = LDA(0, 1), a10 = LDA(1, 0), a11 = LDA(1, 1);
      if (pf) stageHT(Ap, &As[anext][0], 0, kt + 2, row0);
      asm volatile("s_barrier" ::: "memory");
      asm volatile("s_waitcnt lgkmcnt(0)" ::: "memory");
      __builtin_amdgcn_s_setprio(1);
      MFMA_PAIR(0, 1, a00, a01, a10, a11)
      __builtin_amdgcn_s_setprio(0);
      asm volatile("s_barrier" ::: "memory");
    }
    {
      short8 a00 = LDA(2, 0), a01 = LDA(2, 1), a10 = LDA(3, 0), a11 = LDA(3, 1);
      if (pf) stageHT(Ap, &As[anext][0], 1, kt + 2, row0);
      asm volatile("s_barrier" ::: "memory");
      asm volatile("s_waitcnt lgkmcnt(0)" ::: "memory");
      __builtin_amdgcn_s_setprio(1);
      MFMA_PAIR(2, 3, a00, a01, a10, a11)
      __builtin_amdgcn_s_setprio(0);
      asm volatile("s_barrier" ::: "memory");
    }
    {
      short8 a00 = LDA(4, 0), a01 = LDA(4, 1), a10 = LDA(5, 0), a11 = LDA(5, 1);
      if (pf) stageHT(Bp, &Bs[bbuf][0], 0, kt + 2, col0);
      asm volatile("s_barrier" ::: "memory");
      asm volatile("s_waitcnt lgkmcnt(0)" ::: "memory");
      __builtin_amdgcn_s_setprio(1);
      MFMA_PAIR(4, 5, a00, a01, a10, a11)
      __builtin_amdgcn_s_setprio(0);
      asm volatile("s_barrier" ::: "memory");
    }
    {
      short8 a00 = LDA(6, 0), a01 = LDA(6, 1), a10 = LDA(7, 0), a11 = LDA(7, 1);
      if (pf) stageHT(Bp, &Bs[bbuf][0], 1, kt + 2, col0);
      asm volatile("s_barrier" ::: "memory");
      asm volatile("s_waitcnt lgkmcnt(0)" ::: "memory");
      __builtin_amdgcn_s_setprio(1);
      MFMA_PAIR(6, 7, a00, a01, a10, a11)
      __builtin_amdgcn_s_setprio(0);
      if (pf) {
        asm volatile("s_waitcnt vmcnt(8)" ::: "memory");
      } else {
        asm volatile("s_waitcnt vmcnt(0)" ::: "memory");
      }
      asm volatile("s_barrier" ::: "memory");
    }
  }
#undef LDA
#undef MFMA_PAIR

#pragma unroll
  for (int mi = 0; mi < 8; ++mi) {
#pragma unroll
    for (int ni = 0; ni < 4; ++ni) {
#pragma unroll
      for (int i = 0; i < 4; ++i) {
        int grow = row0 + wm * 128 + mi * 16 + quad * 4 + i;
        int gcol = col0 + wn * 64 + ni * 16 + lrow;
        float val = acc[mi][ni][i];
        if (z != 2) {
          if (z == 0) val *= SCALE_LOG2E;  // pre-scale Q for exp2-direct attn
          int b = grow >> 10, n = grow & 1023;
          int h = gcol >> 7, p = (gcol >> 6) & 1, d = gcol & 63;
          unsigned short* dst = (z == 0) ? Qd : Kd;
          dst[((size_t)((b * 16 + h) * 2048) + n * 2 + p) * 64 + d] = f2bf(val);
        } else {
          int h = grow >> 7, p = (grow >> 6) & 1, d = grow & 63;
          int b = gcol >> 10, n = gcol & 1023;
          Vd[((size_t)((b * 16 + h) * 64 + d)) * 2048 + n * 2 + p] = f2bf(val);
        }
      }
    }
  }
}

// ---------------------------------------------------------------------------
// Output GEMM, depth-2 pipeline: 64x64 tile, BK=64, TRIPLE-buffered A/B
// (48 KB LDS), ONE barrier + one counted vmcnt(4) per K-tile. Grid (32,16)
// = 512 blocks = 2/CU (TLP), 4 waves (2x2). stage(kt+2) issued after the
// barrier (3-buffer rotation makes the read-done barrier unnecessary:
// entering iter kt implies all waves finished iter kt-1's reads).
__global__ __launch_bounds__(256) void gemm64p(
    const unsigned short* __restrict__ A,      // [2048 x 2048] row-major
    const unsigned short* __restrict__ Bbase,  // [1024 x 2048] (B^T form)
    float* __restrict__ Cf) {                  // [2048 x 1024]
  __shared__ unsigned short As[3][64 * 64];    // 24 KB
  __shared__ unsigned short Bs[3][64 * 64];    // 24 KB
  constexpr int K = 2048, N = 1024, NT = 32;   // K / 64
  const int t = threadIdx.x;
  const int wave = t >> 6, lane = t & 63, lrow = lane & 15, quad = lane >> 4;
  const int wm = wave >> 1, wn = wave & 1;     // 2x2 wave grid, 32x32 each
  const int row0 = blockIdx.x * 64, col0 = blockIdx.y * 64;
  const int srow8 = lane >> 3;
  const int sslot = (lane & 7) ^ srow8;        // pre-swizzled global slot
  const int swz = lrow & 7;

  // per wave per tile: 2 issues A (16 rows) + 2 issues B = 4 -> vmcnt(4)
  auto stage = [&](int kt, int buf) {
#pragma unroll
    for (int j = 0; j < 2; ++j) {
      const int rloc = wave * 16 + j * 8;
      const unsigned short* ga =
          A + (size_t)(row0 + rloc + srow8) * K + kt * 64 + sslot * 8;
      __builtin_amdgcn_global_load_lds(
          (const __attribute__((address_space(1))) unsigned int*)ga,
          (__attribute__((address_space(3))) unsigned int*)(&As[buf][rloc * 64]),
          16, 0, 0);
      const unsigned short* gb =
          Bbase + (size_t)(col0 + rloc + srow8) * K + kt * 64 + sslot * 8;
      __builtin_amdgcn_global_load_lds(
          (const __attribute__((address_space(1))) unsigned int*)gb,
          (__attribute__((address_space(3))) unsigned int*)(&Bs[buf][rloc * 64]),
          16, 0, 0);
    }
  };

  f32x4 acc[2][2];
#pragma unroll
  for (int mi = 0; mi < 2; ++mi)
#pragma unroll
    for (int ni = 0; ni < 2; ++ni) acc[mi][ni] = (f32x4){0.f, 0.f, 0.f, 0.f};

  stage(0, 0);
  stage(1, 1);

  for (int kt = 0; kt < NT; ++kt) {
    const int buf = kt % 3;
    if (kt < NT - 1) {
      asm volatile("s_waitcnt vmcnt(4)" ::: "memory");  // tile kt landed
    } else {
      asm volatile("s_waitcnt vmcnt(0)" ::: "memory");
    }
    asm volatile("s_barrier" ::: "memory");
    if (kt + 2 < NT) stage(kt + 2, (kt + 2) % 3);

    const unsigned short* __restrict__ Ab = &As[buf][0];
    const unsigned short* __restrict__ Bb = &Bs[buf][0];
    short8 af[2][2], bf[2][2];
#pragma unroll
    for (int mi = 0; mi < 2; ++mi)
#pragma unroll
      for (int ks = 0; ks < 2; ++ks)
        af[mi][ks] = *(const short8*)(
            Ab + (wm * 32 + mi * 16 + lrow) * 64 + (((ks * 4 + quad) ^ swz) * 8));
#pragma unroll
    for (int ni = 0; ni < 2; ++ni)
#pragma unroll
      for (int ks = 0; ks < 2; ++ks)
        bf[ni][ks] = *(const short8*)(
            Bb + (wn * 32 + ni * 16 + lrow) * 64 + (((ks * 4 + quad) ^ swz) * 8));
    __builtin_amdgcn_s_setprio(1);
#pragma unroll
    for (int mi = 0; mi < 2; ++mi)
#pragma unroll
      for (int ni = 0; ni < 2; ++ni) {
        acc[mi][ni] = __builtin_amdgcn_mfma_f32_16x16x32_bf16(
            af[mi][0], bf[ni][0], acc[mi][ni], 0, 0, 0);
        acc[mi][ni] = __builtin_amdgcn_mfma_f32_16x16x32_bf16(
            af[mi][1], bf[ni][1], acc[mi][ni], 0, 0, 0);
      }
    __builtin_amdgcn_s_setprio(0);
  }

#pragma unroll
  for (int mi = 0; mi < 2; ++mi)
#pragma unroll
    for (int ni = 0; ni < 2; ++ni)
#pragma unroll
      for (int i = 0; i < 4; ++i) {
        int grow = row0 + wm * 32 + mi * 16 + quad * 4 + i;
        int gcol = col0 + wn * 32 + ni * 16 + lrow;
        Cf[(size_t)grow * N + gcol] = acc[mi][ni][i];
      }
}

// ---------------------------------------------------------------------------
// Causal flash attention v4: KVBLK=128 per iteration, SINGLE-buffer LDS
// (Ks[128][64] + Vs[64][128] = 32 KB, both XOR-swizzled), T14 register
// staging: global->reg loads for tile i+1 issued during iter i (one full
// iteration of VMEM flight), published via swizzled ds_write + one
// lgkm+barrier. Sync events per 128 kv-cols: 2 barriers + 1 vmcnt(0)
// (previously 4 barriers + 2 vmcnt). In-register P (16x16x16 PV MFMA),
// Q pre-scaled. Masked-tail extra FLOPs: +3%.
__global__ __launch_bounds__(256, 4) void attn_kernel(
    const unsigned short* __restrict__ Qv, const unsigned short* __restrict__ Kv,
    const unsigned short* __restrict__ Vt, unsigned short* __restrict__ Aov) {
  __shared__ unsigned short Ks[128 * 64];   // [kv 128][d 64]
  __shared__ unsigned short Vs[64 * 128];   // [d 64][kv 128]
  const int bh = blockIdx.x;
  const int yy = blockIdx.y;
  const int qt = (yy < 16) ? yy : (47 - yy);
  const int t = threadIdx.x;
  const int w = t >> 6, lane = t & 63, lq = lane & 15, quad = lane >> 4;
  const int l3 = lq & 7;

  const unsigned short* Qh = Qv + (size_t)bh * SV_ * D_;
  const unsigned short* Kh = Kv + (size_t)bh * SV_ * D_;
  const unsigned short* Vh = Vt + (size_t)bh * D_ * SV_;

  const int qrow = qt * 64 + w * 16 + lq;  // this lane's q row
  short8 bq0 = *(const short8*)(Qh + (size_t)qrow * 64 + quad * 8);
  short8 bq1 = *(const short8*)(Qh + (size_t)qrow * 64 + 32 + quad * 8);

  // ---- register staging geometry (whole block stages one 128-kv tile) ----
  // K tile: 128 rows x 64 d (16 KB). Each thread covers 64 B = 4 granules:
  //   row = t>>1, slots (t&1)*4 .. +3  (linear global, swizzled ds_write)
  const int krow = t >> 1;
  const int kslot0 = (t & 1) * 4;
  // V tile: 64 d-rows x 128 kv (16 KB): row = t>>2, slots (t&3)*4 .. +3
  const int vrow = t >> 2;
  const int vslot0 = (t & 3) * 4;
  const unsigned short* Kgl = Kh + (size_t)krow * 64 + kslot0 * 8;
  const unsigned short* Vgl = Vh + (size_t)vrow * SV_ + vslot0 * 8;

  int kw_addr[4], vw_addr[4];  // LDS byte addrs, swizzled
#pragma unroll
  for (int q = 0; q < 4; ++q) {
    const int ks = kslot0 + q;
    kw_addr[q] = krow * 128 + ((ks ^ (krow & 7)) * 16);
    const int vs = vslot0 + q;
    vw_addr[q] = vrow * 256 + (((vs & 8) | ((vs & 7) ^ (vrow & 7))) * 16);
  }

  int4 kreg[4], vreg[4];
  auto load_tile = [&](int i) {
#pragma unroll
    for (int q = 0; q < 4; ++q) {
      kreg[q] = *(const int4*)(Kgl + (size_t)i * 8192 + q * 8);
      vreg[q] = *(const int4*)(Vgl + i * 128 + q * 8);
    }
  };

  float l_sum = 0.f;
  f32x4 o_acc[4];
#pragma unroll
  for (int nd = 0; nd < 4; ++nd) o_acc[nd] = (f32x4){0.f, 0.f, 0.f, 0.f};

  const int nt128 = (qt >> 1) + 1;
  load_tile(0);

  for (int i = 0; i < nt128; ++i) {
    __builtin_amdgcn_s_barrier();               // all waves done reading LDS
    asm volatile("s_waitcnt vmcnt(0)" ::: "memory");  // tile-i regs landed
#pragma unroll
    for (int q = 0; q < 4; ++q)
      *(int4*)((char*)Ks + kw_addr[q]) = kreg[q];
#pragma unroll
    for (int q = 0; q < 4; ++q)
      *(int4*)((char*)Vs + vw_addr[q]) = vreg[q];
    if (i + 1 < nt128) load_tile(i + 1);        // next tile: full-iter flight
    asm volatile("s_waitcnt lgkmcnt(0)" ::: "memory");
    __builtin_amdgcn_s_barrier();               // all writes visible

    const bool diag = (i == nt128 - 1);
    float rs = 0.f;
    __builtin_amdgcn_s_setprio(1);
#pragma unroll
    for (int t8 = 0; t8 < 8; ++t8) {
      // K fragments (b128, swizzled granules)
      short8 k0 = *(const short8*)(&Ks[0] + (t8 * 16 + lq) * 64 + (((0 * 4 + quad) ^ l3) * 8));
      short8 k1 = *(const short8*)(&Ks[0] + (t8 * 16 + lq) * 64 + (((1 * 4 + quad) ^ l3) * 8));
      f32x4 z = (f32x4){0.f, 0.f, 0.f, 0.f};
      z = __builtin_amdgcn_mfma_f32_16x16x32_bf16(k0, bq0, z, 0, 0, 0);
      z = __builtin_amdgcn_mfma_f32_16x16x32_bf16(k1, bq1, z, 0, 0, 0);

      float p[4];
#pragma unroll
      for (int ii = 0; ii < 4; ++ii) {
        float e = EXP2(z[ii]);
        if (diag)
          e = (i * 128 + t8 * 16 + quad * 4 + ii > qrow) ? 0.f : e;
        p[ii] = e;
        rs += e;
      }
      unsigned ww[2];
      ww[0] = pack_bf2(p[0], p[1]);
      ww[1] = pack_bf2(p[2], p[3]);
      short4b pb;
      __builtin_memcpy(&pb, ww, 8);

      const int vg = t8 * 2 + (quad >> 1);
      const int vbyte = ((vg & 8) | ((vg & 7) ^ l3)) * 16 + (quad & 1) * 8;
#pragma unroll
      for (int nd = 0; nd < 4; ++nd) {
        short4b va4;
        __builtin_memcpy(&va4, (const char*)Vs + (nd * 16 + lq) * 256 + vbyte, 8);
        o_acc[nd] = __builtin_amdgcn_mfma_f32_16x16x16bf16_1k(va4, pb,
                                                              o_acc[nd], 0, 0, 0);
      }
    }
    __builtin_amdgcn_s_setprio(0);
    l_sum += rs;
  }

  // final cross-quad row-sum reduction
  l_sum += __shfl_xor(l_sum, 16);
  l_sum += __shfl_xor(l_sum, 32);

  const int b = bh >> 4, h = bh & 15;
  const float inv = 1.0f / l_sum;
  const int n = qrow >> 1, p = qrow & 1;
  unsigned short* dst = Aov + ((size_t)(b * 1024 + n)) * 2048 + (h * 2 + p) * 64;
#pragma unroll
  for (int nd = 0; nd < 4; ++nd) {
    uint2 dw;
    dw.x = pack_bf2(o_acc[nd][0] * inv, o_acc[nd][1] * inv);
    dw.y = pack_bf2(o_acc[nd][2] * inv, o_acc[nd][3] * inv);
    *(uint2*)(dst + nd * 16 + quad * 4) = dw;
  }
}

// ---------------------------------------------------------------------------
extern "C" void kernel_launch(void* const* d_in, const int* in_sizes, int n_in,
                              void* d_out, int out_size, void* d_ws, size_t ws_size,
                              hipStream_t stream) {
  (void)in_sizes; (void)n_in; (void)out_size; (void)ws_size;
  const float* x    = (const float*)d_in[0];
  const float* Wq   = (const float*)d_in[1];
  const float* Wk   = (const float*)d_in[2];
  const float* Wv   = (const float*)d_in[3];
  const float* Wo   = (const float*)d_in[4];
  const float* aq   = (const float*)d_in[5];
  const float* ak   = (const float*)d_in[6];
  const float* av   = (const float*)d_in[7];
  const float* coll = (const float*)d_in[8];
  float* out = (float*)d_out;

  char* ws = (char*)d_ws;
  const size_t MB = 1024 * 1024;
  unsigned short* Xb    = (unsigned short*)(ws);            // 4 MB  [0,4)
  unsigned short* Woeff = (unsigned short*)(ws + 4 * MB);   // 4 MB  [4,8)
  unsigned short* Weff  = (unsigned short*)(ws + 8 * MB);   // 12 MB [8,20)
  unsigned short* Qv    = (unsigned short*)(ws + 20 * MB);  // 8 MB  [20,28)
  unsigned short* Kv    = (unsigned short*)(ws + 28 * MB);  // 8 MB  [28,36)
  unsigned short* Vt    = (unsigned short*)(ws + 36 * MB);  // 8 MB  [36,44)
  // Weff dead after QKV GEMM; reuse:
  unsigned short* Aov   = (unsigned short*)(ws + 8 * MB);   // 8 MB  [8,16)

  cast_f32_bf16<<<dim3(1024), dim3(256), 0, stream>>>(x, Xb, (B_ * S_ * HID_) / 4);
  weff_kernel<<<dim3(64, 3), dim3(256), 0, stream>>>(Wq, Wk, Wv, aq, ak, av, Weff);
  qkv_gemm256<<<dim3(8, 8, 3), dim3(512), 0, stream>>>(Xb, Weff, Qv, Kv, Vt);
  attn_kernel<<<dim3(32, 32), dim3(256), 0, stream>>>(Qv, Kv, Vt, Aov);
  woeff_kernel<<<dim3(1024), dim3(256), 0, stream>>>(Wo, coll, Woeff);
  gemm64p<<<dim3(32, 16), dim3(256), 0, stream>>>(Aov, Woeff, out);
}

// Round 7
// 255.639 us; speedup vs baseline: 1.0281x; 1.0281x over previous
//
#include <hip/hip_runtime.h>
#include <hip/hip_bf16.h>

// Problem constants
#define B_    2
#define S_    1024
#define HID_  1024
#define H_    16
#define P_    2
#define D_    64
#define SV_   2048   // S_*P_
#define NBH_  32     // B_*H_
// SCALE * log2(e) = 0.125 * 1.4426950408889634
#define SCALE_LOG2E 0.18033688f

typedef __attribute__((ext_vector_type(8))) short short8;
typedef __attribute__((ext_vector_type(4))) short short4b;
typedef __attribute__((ext_vector_type(4))) float f32x4;

#if __has_builtin(__builtin_amdgcn_exp2f)
#define EXP2(x) __builtin_amdgcn_exp2f(x)
#else
#define EXP2(x) exp2f(x)
#endif

__device__ __forceinline__ unsigned short f2bf(float f) {
  union { float f; unsigned u; } v; v.f = f;
  unsigned r = v.u + 0x7fffu + ((v.u >> 16) & 1u);
  return (unsigned short)(r >> 16);
}
__device__ __forceinline__ unsigned pack_bf2(float a, float b) {
  __hip_bfloat162 h = __float22bfloat162_rn(make_float2(a, b));
  unsigned u; __builtin_memcpy(&u, &h, 4);
  return u;
}

// ---------------------------------------------------------------------------
__global__ __launch_bounds__(256) void cast_f32_bf16(
    const float* __restrict__ src, unsigned short* __restrict__ dst, int n4) {
  int i = blockIdx.x * blockDim.x + threadIdx.x;
  int stride = gridDim.x * blockDim.x;
  for (; i < n4; i += stride) {
    float4 v = ((const float4*)src)[i];
    ushort4 o;
    o.x = f2bf(v.x); o.y = f2bf(v.y); o.z = f2bf(v.z); o.w = f2bf(v.w);
    ((ushort4*)dst)[i] = o;
  }
}

// ---------------------------------------------------------------------------
// Weff[t][r=(h*128+p*64+d)][e] = sum_m A[m*32+hp] * W[m*64+d][e]
__global__ __launch_bounds__(256) void weff_kernel(
    const float* __restrict__ Wq, const float* __restrict__ Wk,
    const float* __restrict__ Wv,
    const float* __restrict__ aq, const float* __restrict__ ak,
    const float* __restrict__ av,
    unsigned short* __restrict__ Weff) {
  __shared__ float Al[16][32];
  const int d = blockIdx.x;   // 0..63
  const int t = blockIdx.y;   // 0..2
  const float* W = (t == 0) ? Wq : ((t == 1) ? Wk : Wv);
  const float* A = (t == 0) ? aq : ((t == 1) ? ak : av);
  const int tid = threadIdx.x;
  for (int idx = tid; idx < 512; idx += 256) Al[idx >> 5][idx & 31] = A[idx];
  __syncthreads();
  const int e = tid * 4;
  float wr[16][4];
#pragma unroll
  for (int m = 0; m < 16; ++m) {
    float4 v = *(const float4*)(W + (size_t)(m * 64 + d) * 1024 + e);
    wr[m][0] = v.x; wr[m][1] = v.y; wr[m][2] = v.z; wr[m][3] = v.w;
  }
  for (int hp = 0; hp < 32; ++hp) {
    float acc0 = 0.f, acc1 = 0.f, acc2 = 0.f, acc3 = 0.f;
#pragma unroll
    for (int m = 0; m < 16; ++m) {
      float al = Al[m][hp];
      acc0 += al * wr[m][0]; acc1 += al * wr[m][1];
      acc2 += al * wr[m][2]; acc3 += al * wr[m][3];
    }
    int r = (hp >> 1) * 128 + (hp & 1) * 64 + d;
    ushort4 ov;
    ov.x = f2bf(acc0); ov.y = f2bf(acc1); ov.z = f2bf(acc2); ov.w = f2bf(acc3);
    *(ushort4*)(Weff + ((size_t)t * 2048 + r) * 1024 + e) = ov;
  }
}

// ---------------------------------------------------------------------------
// Woeff[f][o*64+d] = sum_h coll[h*32+o] * Wo[f][h*64+d]   (bf16 out)
__global__ __launch_bounds__(256) void woeff_kernel(
    const float* __restrict__ Wo, const float* __restrict__ coll,
    unsigned short* __restrict__ Woeff) {
  __shared__ float wrow[1024];
  __shared__ float cl[512];
  const int f = blockIdx.x;
  const int tid = threadIdx.x;
  for (int idx = tid; idx < 512; idx += 256) cl[idx] = coll[idx];
  for (int idx = tid; idx < 1024; idx += 256) wrow[idx] = Wo[(size_t)f * 1024 + idx];
  __syncthreads();
  for (int idx = tid; idx < 2048; idx += 256) {
    int o = idx >> 6, d = idx & 63;
    float acc = 0.f;
#pragma unroll
    for (int h = 0; h < 16; ++h) acc += wrow[h * 64 + d] * cl[h * 32 + o];
    Woeff[(size_t)f * 2048 + idx] = f2bf(acc);
  }
}

// ---------------------------------------------------------------------------
// Unified QKV GEMM — 256x256-tile 8-phase schedule, DEPTH-2.5 PIPELINE.
// (unchanged; Q output pre-scaled by SCALE_LOG2E)
__global__ __launch_bounds__(512) void qkv_gemm256(
    const unsigned short* __restrict__ Xb,
    const unsigned short* __restrict__ Weff,
    unsigned short* __restrict__ Qd, unsigned short* __restrict__ Kd,
    unsigned short* __restrict__ Vd) {
  __shared__ unsigned short As[3][256 * 64];   // 96 KiB
  __shared__ unsigned short Bs[2][256 * 64];   // 64 KiB  -> 160 KiB total
  constexpr int K = 1024;
  constexpr int NT = 16;                        // K / 64
  const int t = threadIdx.x;
  const int wave = t >> 6, lane = t & 63, lrow = lane & 15, quad = lane >> 4;
  const int wm = wave >> 2, wn = wave & 3;      // 2M x 4N wave grid
  const int z = blockIdx.z;
  const int row0 = blockIdx.x * 256, col0 = blockIdx.y * 256;
  const unsigned short* Ap = (z == 2) ? (Weff + (size_t)2 * 2048 * 1024) : Xb;
  const unsigned short* Bp = (z == 2) ? Xb : (Weff + (size_t)z * 2048 * 1024);

  const int srow8 = lane >> 3;                 // row within the 8-row chunk
  const int sslot = (lane & 7) ^ srow8;        // pre-swizzled global 16B slot

  auto stageHT = [&](const unsigned short* __restrict__ gsrc,
                     unsigned short* __restrict__ ldsbase,
                     int half, int kt, int trow0) {
#pragma unroll
    for (int j = 0; j < 2; ++j) {
      const int rloc = half * 128 + wave * 16 + j * 8;  // wave-uniform
      const unsigned short* g =
          gsrc + (size_t)(trow0 + rloc + srow8) * K + kt * 64 + sslot * 8;
      __builtin_amdgcn_global_load_lds(
          (const __attribute__((address_space(1))) unsigned int*)g,
          (__attribute__((address_space(3))) unsigned int*)(ldsbase + rloc * 64),
          16, 0, 0);
    }
  };

  f32x4 acc[8][4];
#pragma unroll
  for (int mi = 0; mi < 8; ++mi)
#pragma unroll
    for (int ni = 0; ni < 4; ++ni) acc[mi][ni] = (f32x4){0.f, 0.f, 0.f, 0.f};

  stageHT(Ap, &As[0][0], 0, 0, row0);
  stageHT(Ap, &As[0][0], 1, 0, row0);
  stageHT(Bp, &Bs[0][0], 0, 0, col0);
  stageHT(Bp, &Bs[0][0], 1, 0, col0);
  stageHT(Ap, &As[1][0], 0, 1, row0);
  stageHT(Ap, &As[1][0], 1, 1, row0);
  stageHT(Bp, &Bs[1][0], 0, 1, col0);
  stageHT(Bp, &Bs[1][0], 1, 1, col0);
  asm volatile("s_waitcnt vmcnt(8)" ::: "memory");
  asm volatile("s_barrier" ::: "memory");

  const int swz = lrow & 7;

#define LDA(mi, ks)                                                         \
  (*(const short8*)(Ab + (wm * 128 + (mi)*16 + lrow) * 64 +                 \
                    ((((ks)*4 + quad) ^ swz) * 8)))

#define MFMA_PAIR(mA, mB, a00, a01, a10, a11)                               \
  _Pragma("unroll") for (int ni = 0; ni < 4; ++ni) {                        \
    acc[mA][ni] = __builtin_amdgcn_mfma_f32_16x16x32_bf16(                  \
        a00, bfrag[ni][0], acc[mA][ni], 0, 0, 0);                           \
    acc[mA][ni] = __builtin_amdgcn_mfma_f32_16x16x32_bf16(                  \
        a01, bfrag[ni][1], acc[mA][ni], 0, 0, 0);                           \
    acc[mB][ni] = __builtin_amdgcn_mfma_f32_16x16x32_bf16(                  \
        a10, bfrag[ni][0], acc[mB][ni], 0, 0, 0);                           \
    acc[mB][ni] = __builtin_amdgcn_mfma_f32_16x16x32_bf16(                  \
        a11, bfrag[ni][1], acc[mB][ni], 0, 0, 0);                           \
  }

  for (int kt = 0; kt < NT; ++kt) {
    const int abuf = kt % 3;
    const int anext = (kt + 2) % 3;
    const int bbuf = kt & 1;
    const bool pf = (kt + 2 < NT);
    const unsigned short* __restrict__ Ab = &As[abuf][0];
    const unsigned short* __restrict__ Bb = &Bs[bbuf][0];

    short8 bfrag[4][2];
    {
#pragma unroll
      for (int ni = 0; ni < 4; ++ni) {
        const int R = wn * 64 + ni * 16 + lrow;
#pragma unroll
        for (int ks = 0; ks < 2; ++ks)
          bfrag[ni][ks] =
              *(const short8*)(Bb + R * 64 + (((ks * 4 + quad) ^ swz) * 8));
      }
      short8 a00 = LDA(0, 0), a01 = LDA(0, 1), a10 = LDA(1, 0), a11 = LDA(1, 1);
      if (pf) stageHT(Ap, &As[anext][0], 0, kt + 2, row0);
      asm volatile("s_barrier" ::: "memory");
      asm volatile("s_waitcnt lgkmcnt(0)" ::: "memory");
      __builtin_amdgcn_s_setprio(1);
      MFMA_PAIR(0, 1, a00, a01, a10, a11)
      __builtin_amdgcn_s_setprio(0);
      asm volatile("s_barrier" ::: "memory");
    }
    {
      short8 a00 = LDA(2, 0), a01 = LDA(2, 1), a10 = LDA(3, 0), a11 = LDA(3, 1);
      if (pf) stageHT(Ap, &As[anext][0], 1, kt + 2, row0);
      asm volatile("s_barrier" ::: "memory");
      asm volatile("s_waitcnt lgkmcnt(0)" ::: "memory");
      __builtin_amdgcn_s_setprio(1);
      MFMA_PAIR(2, 3, a00, a01, a10, a11)
      __builtin_amdgcn_s_setprio(0);
      asm volatile("s_barrier" ::: "memory");
    }
    {
      short8 a00 = LDA(4, 0), a01 = LDA(4, 1), a10 = LDA(5, 0), a11 = LDA(5, 1);
      if (pf) stageHT(Bp, &Bs[bbuf][0], 0, kt + 2, col0);
      asm volatile("s_barrier" ::: "memory");
      asm volatile("s_waitcnt lgkmcnt(0)" ::: "memory");
      __builtin_amdgcn_s_setprio(1);
      MFMA_PAIR(4, 5, a00, a01, a10, a11)
      __builtin_amdgcn_s_setprio(0);
      asm volatile("s_barrier" ::: "memory");
    }
    {
      short8 a00 = LDA(6, 0), a01 = LDA(6, 1), a10 = LDA(7, 0), a11 = LDA(7, 1);
      if (pf) stageHT(Bp, &Bs[bbuf][0], 1, kt + 2, col0);
      asm volatile("s_barrier" ::: "memory");
      asm volatile("s_waitcnt lgkmcnt(0)" ::: "memory");
      __builtin_amdgcn_s_setprio(1);
      MFMA_PAIR(6, 7, a00, a01, a10, a11)
      __builtin_amdgcn_s_setprio(0);
      if (pf) {
        asm volatile("s_waitcnt vmcnt(8)" ::: "memory");
      } else {
        asm volatile("s_waitcnt vmcnt(0)" ::: "memory");
      }
      asm volatile("s_barrier" ::: "memory");
    }
  }
#undef LDA
#undef MFMA_PAIR

#pragma unroll
  for (int mi = 0; mi < 8; ++mi) {
#pragma unroll
    for (int ni = 0; ni < 4; ++ni) {
#pragma unroll
      for (int i = 0; i < 4; ++i) {
        int grow = row0 + wm * 128 + mi * 16 + quad * 4 + i;
        int gcol = col0 + wn * 64 + ni * 16 + lrow;
        float val = acc[mi][ni][i];
        if (z != 2) {
          if (z == 0) val *= SCALE_LOG2E;  // pre-scale Q for exp2-direct attn
          int b = grow >> 10, n = grow & 1023;
          int h = gcol >> 7, p = (gcol >> 6) & 1, d = gcol & 63;
          unsigned short* dst = (z == 0) ? Qd : Kd;
          dst[((size_t)((b * 16 + h) * 2048) + n * 2 + p) * 64 + d] = f2bf(val);
        } else {
          int h = grow >> 7, p = (grow >> 6) & 1, d = grow & 63;
          int b = gcol >> 10, n = gcol & 1023;
          Vd[((size_t)((b * 16 + h) * 64 + d)) * 2048 + n * 2 + p] = f2bf(val);
        }
      }
    }
  }
}

// ---------------------------------------------------------------------------
// Output GEMM, depth-2 pipeline: 64x64 tile, BK=64, TRIPLE-buffered A/B,
// ONE barrier + counted vmcnt(4) per K-tile. Grid (32,16) = 2 blocks/CU.
__global__ __launch_bounds__(256) void gemm64p(
    const unsigned short* __restrict__ A,      // [2048 x 2048] row-major
    const unsigned short* __restrict__ Bbase,  // [1024 x 2048] (B^T form)
    float* __restrict__ Cf) {                  // [2048 x 1024]
  __shared__ unsigned short As[3][64 * 64];    // 24 KB
  __shared__ unsigned short Bs[3][64 * 64];    // 24 KB
  constexpr int K = 2048, N = 1024, NT = 32;   // K / 64
  const int t = threadIdx.x;
  const int wave = t >> 6, lane = t & 63, lrow = lane & 15, quad = lane >> 4;
  const int wm = wave >> 1, wn = wave & 1;     // 2x2 wave grid, 32x32 each
  const int row0 = blockIdx.x * 64, col0 = blockIdx.y * 64;
  const int srow8 = lane >> 3;
  const int sslot = (lane & 7) ^ srow8;        // pre-swizzled global slot
  const int swz = lrow & 7;

  auto stage = [&](int kt, int buf) {
#pragma unroll
    for (int j = 0; j < 2; ++j) {
      const int rloc = wave * 16 + j * 8;
      const unsigned short* ga =
          A + (size_t)(row0 + rloc + srow8) * K + kt * 64 + sslot * 8;
      __builtin_amdgcn_global_load_lds(
          (const __attribute__((address_space(1))) unsigned int*)ga,
          (__attribute__((address_space(3))) unsigned int*)(&As[buf][rloc * 64]),
          16, 0, 0);
      const unsigned short* gb =
          Bbase + (size_t)(col0 + rloc + srow8) * K + kt * 64 + sslot * 8;
      __builtin_amdgcn_global_load_lds(
          (const __attribute__((address_space(1))) unsigned int*)gb,
          (__attribute__((address_space(3))) unsigned int*)(&Bs[buf][rloc * 64]),
          16, 0, 0);
    }
  };

  f32x4 acc[2][2];
#pragma unroll
  for (int mi = 0; mi < 2; ++mi)
#pragma unroll
    for (int ni = 0; ni < 2; ++ni) acc[mi][ni] = (f32x4){0.f, 0.f, 0.f, 0.f};

  stage(0, 0);
  stage(1, 1);

  for (int kt = 0; kt < NT; ++kt) {
    const int buf = kt % 3;
    if (kt < NT - 1) {
      asm volatile("s_waitcnt vmcnt(4)" ::: "memory");  // tile kt landed
    } else {
      asm volatile("s_waitcnt vmcnt(0)" ::: "memory");
    }
    asm volatile("s_barrier" ::: "memory");
    if (kt + 2 < NT) stage(kt + 2, (kt + 2) % 3);

    const unsigned short* __restrict__ Ab = &As[buf][0];
    const unsigned short* __restrict__ Bb = &Bs[buf][0];
    short8 af[2][2], bf[2][2];
#pragma unroll
    for (int mi = 0; mi < 2; ++mi)
#pragma unroll
      for (int ks = 0; ks < 2; ++ks)
        af[mi][ks] = *(const short8*)(
            Ab + (wm * 32 + mi * 16 + lrow) * 64 + (((ks * 4 + quad) ^ swz) * 8));
#pragma unroll
    for (int ni = 0; ni < 2; ++ni)
#pragma unroll
      for (int ks = 0; ks < 2; ++ks)
        bf[ni][ks] = *(const short8*)(
            Bb + (wn * 32 + ni * 16 + lrow) * 64 + (((ks * 4 + quad) ^ swz) * 8));
    __builtin_amdgcn_s_setprio(1);
#pragma unroll
    for (int mi = 0; mi < 2; ++mi)
#pragma unroll
      for (int ni = 0; ni < 2; ++ni) {
        acc[mi][ni] = __builtin_amdgcn_mfma_f32_16x16x32_bf16(
            af[mi][0], bf[ni][0], acc[mi][ni], 0, 0, 0);
        acc[mi][ni] = __builtin_amdgcn_mfma_f32_16x16x32_bf16(
            af[mi][1], bf[ni][1], acc[mi][ni], 0, 0, 0);
      }
    __builtin_amdgcn_s_setprio(0);
  }

#pragma unroll
  for (int mi = 0; mi < 2; ++mi)
#pragma unroll
    for (int ni = 0; ni < 2; ++ni)
#pragma unroll
      for (int i = 0; i < 4; ++i) {
        int grow = row0 + wm * 32 + mi * 16 + quad * 4 + i;
        int gcol = col0 + wn * 32 + ni * 16 + lrow;
        Cf[(size_t)grow * N + gcol] = acc[mi][ni][i];
      }
}

// ---------------------------------------------------------------------------
// Causal flash attention v5: KVBLK=128, single-buffer LDS (32 KB), T14
// register staging in NAMED SSA VARIABLES (no arrays, no lambda capture —
// v4's by-reference lambda capture of int4 arrays made them address-taken
// allocas, and every asm "memory" clobber then forced scratch spills:
// 259 MB of HBM write traffic). Loads for tile i+1 issue right after tile
// i's LDS publish and fly for a full iteration. In-register P (16x16x16
// PV MFMA), Q pre-scaled by SCALE_LOG2E.
__global__ __launch_bounds__(256, 4) void attn_kernel(
    const unsigned short* __restrict__ Qv, const unsigned short* __restrict__ Kv,
    const unsigned short* __restrict__ Vt, unsigned short* __restrict__ Aov) {
  __shared__ unsigned short Ks[128 * 64];   // [kv 128][d 64] swizzled
  __shared__ unsigned short Vs[64 * 128];   // [d 64][kv 128] swizzled
  const int bh = blockIdx.x;
  const int yy = blockIdx.y;
  const int qt = (yy < 16) ? yy : (47 - yy);
  const int t = threadIdx.x;
  const int w = t >> 6, lane = t & 63, lq = lane & 15, quad = lane >> 4;
  const int l3 = lq & 7;

  const unsigned short* Qh = Qv + (size_t)bh * SV_ * D_;
  const unsigned short* Kh = Kv + (size_t)bh * SV_ * D_;
  const unsigned short* Vh = Vt + (size_t)bh * D_ * SV_;

  const int qrow = qt * 64 + w * 16 + lq;  // this lane's q row
  short8 bq0 = *(const short8*)(Qh + (size_t)qrow * 64 + quad * 8);
  short8 bq1 = *(const short8*)(Qh + (size_t)qrow * 64 + 32 + quad * 8);

  // ---- register staging geometry (whole block stages one 128-kv tile) ----
  // K tile: 128 rows x 64 d. thread covers 4 granules: row=t>>1, slots
  // (t&1)*4..+3. V tile: 64 d-rows x 128 kv: row=t>>2, slots (t&3)*4..+3.
  const int krow = t >> 1;
  const int kslot0 = (t & 1) * 4;
  const int vrow = t >> 2;
  const int vslot0 = (t & 3) * 4;
  const unsigned short* Kgl = Kh + (size_t)krow * 64 + kslot0 * 8;
  const unsigned short* Vgl = Vh + (size_t)vrow * SV_ + vslot0 * 8;

  // Swizzled LDS write byte-addresses as named scalars (no arrays).
  const int kr7 = krow & 7, vr7 = vrow & 7;
  const int kwa0 = krow * 128 + (((kslot0 + 0) ^ kr7) * 16);
  const int kwa1 = krow * 128 + (((kslot0 + 1) ^ kr7) * 16);
  const int kwa2 = krow * 128 + (((kslot0 + 2) ^ kr7) * 16);
  const int kwa3 = krow * 128 + (((kslot0 + 3) ^ kr7) * 16);
  const int vwa0 = vrow * 256 + ((((vslot0 + 0) & 8) | (((vslot0 + 0) & 7) ^ vr7)) * 16);
  const int vwa1 = vrow * 256 + ((((vslot0 + 1) & 8) | (((vslot0 + 1) & 7) ^ vr7)) * 16);
  const int vwa2 = vrow * 256 + ((((vslot0 + 2) & 8) | (((vslot0 + 2) & 7) ^ vr7)) * 16);
  const int vwa3 = vrow * 256 + ((((vslot0 + 3) & 8) | (((vslot0 + 3) & 7) ^ vr7)) * 16);

  int4 k0, k1, k2, k3, v0, v1, v2, v3;   // named SSA staging registers

#define LOAD_TILE(ii)                                                    \
  k0 = *(const int4*)(Kgl + (size_t)(ii) * 8192 + 0);                    \
  k1 = *(const int4*)(Kgl + (size_t)(ii) * 8192 + 8);                    \
  k2 = *(const int4*)(Kgl + (size_t)(ii) * 8192 + 16);                   \
  k3 = *(const int4*)(Kgl + (size_t)(ii) * 8192 + 24);                   \
  v0 = *(const int4*)(Vgl + (ii) * 128 + 0);                             \
  v1 = *(const int4*)(Vgl + (ii) * 128 + 8);                             \
  v2 = *(const int4*)(Vgl + (ii) * 128 + 16);                            \
  v3 = *(const int4*)(Vgl + (ii) * 128 + 24);

  float l_sum = 0.f;
  f32x4 o_acc[4];
#pragma unroll
  for (int nd = 0; nd < 4; ++nd) o_acc[nd] = (f32x4){0.f, 0.f, 0.f, 0.f};

  const int nt128 = (qt >> 1) + 1;
  LOAD_TILE(0)

  for (int i = 0; i < nt128; ++i) {
    asm volatile("s_barrier" ::: "memory");           // all waves done reading
    asm volatile("s_waitcnt vmcnt(0)" ::: "memory");  // tile-i regs landed
    *(int4*)((char*)Ks + kwa0) = k0;
    *(int4*)((char*)Ks + kwa1) = k1;
    *(int4*)((char*)Ks + kwa2) = k2;
    *(int4*)((char*)Ks + kwa3) = k3;
    *(int4*)((char*)Vs + vwa0) = v0;
    *(int4*)((char*)Vs + vwa1) = v1;
    *(int4*)((char*)Vs + vwa2) = v2;
    *(int4*)((char*)Vs + vwa3) = v3;
    if (i + 1 < nt128) { LOAD_TILE(i + 1) }           // full-iteration flight
    asm volatile("s_waitcnt lgkmcnt(0)" ::: "memory");
    asm volatile("s_barrier" ::: "memory");           // writes visible

    const bool diag = (i == nt128 - 1);
    float rs = 0.f;
    __builtin_amdgcn_s_setprio(1);
#pragma unroll
    for (int t8 = 0; t8 < 8; ++t8) {
      short8 ka0 = *(const short8*)(&Ks[0] + (t8 * 16 + lq) * 64 + (((quad) ^ l3) * 8));
      short8 ka1 = *(const short8*)(&Ks[0] + (t8 * 16 + lq) * 64 + (((4 + quad) ^ l3) * 8));
      f32x4 z = (f32x4){0.f, 0.f, 0.f, 0.f};
      z = __builtin_amdgcn_mfma_f32_16x16x32_bf16(ka0, bq0, z, 0, 0, 0);
      z = __builtin_amdgcn_mfma_f32_16x16x32_bf16(ka1, bq1, z, 0, 0, 0);

      float p0 = EXP2(z[0]), p1 = EXP2(z[1]), p2 = EXP2(z[2]), p3 = EXP2(z[3]);
      if (diag) {
        const int kc = i * 128 + t8 * 16 + quad * 4;
        if (kc + 0 > qrow) p0 = 0.f;
        if (kc + 1 > qrow) p1 = 0.f;
        if (kc + 2 > qrow) p2 = 0.f;
        if (kc + 3 > qrow) p3 = 0.f;
      }
      rs += (p0 + p1) + (p2 + p3);
      unsigned w0 = pack_bf2(p0, p1);
      unsigned w1 = pack_bf2(p2, p3);
      unsigned pw[2] = {w0, w1};
      short4b pb;
      __builtin_memcpy(&pb, pw, 8);

      const int vg = t8 * 2 + (quad >> 1);
      const int vbyte = ((vg & 8) | ((vg & 7) ^ l3)) * 16 + (quad & 1) * 8;
#pragma unroll
      for (int nd = 0; nd < 4; ++nd) {
        short4b va4;
        __builtin_memcpy(&va4, (const char*)Vs + (nd * 16 + lq) * 256 + vbyte, 8);
        o_acc[nd] = __builtin_amdgcn_mfma_f32_16x16x16bf16_1k(va4, pb,
                                                              o_acc[nd], 0, 0, 0);
      }
    }
    __builtin_amdgcn_s_setprio(0);
    l_sum += rs;
  }
#undef LOAD_TILE

  // final cross-quad row-sum reduction
  l_sum += __shfl_xor(l_sum, 16);
  l_sum += __shfl_xor(l_sum, 32);

  const int b = bh >> 4, h = bh & 15;
  const float inv = 1.0f / l_sum;
  const int n = qrow >> 1, p = qrow & 1;
  unsigned short* dst = Aov + ((size_t)(b * 1024 + n)) * 2048 + (h * 2 + p) * 64;
#pragma unroll
  for (int nd = 0; nd < 4; ++nd) {
    uint2 dw;
    dw.x = pack_bf2(o_acc[nd][0] * inv, o_acc[nd][1] * inv);
    dw.y = pack_bf2(o_acc[nd][2] * inv, o_acc[nd][3] * inv);
    *(uint2*)(dst + nd * 16 + quad * 4) = dw;
  }
}

// ---------------------------------------------------------------------------
extern "C" void kernel_launch(void* const* d_in, const int* in_sizes, int n_in,
                              void* d_out, int out_size, void* d_ws, size_t ws_size,
                              hipStream_t stream) {
  (void)in_sizes; (void)n_in; (void)out_size; (void)ws_size;
  const float* x    = (const float*)d_in[0];
  const float* Wq   = (const float*)d_in[1];
  const float* Wk   = (const float*)d_in[2];
  const float* Wv   = (const float*)d_in[3];
  const float* Wo   = (const float*)d_in[4];
  const float* aq   = (const float*)d_in[5];
  const float* ak   = (const float*)d_in[6];
  const float* av   = (const float*)d_in[7];
  const float* coll = (const float*)d_in[8];
  float* out = (float*)d_out;

  char* ws = (char*)d_ws;
  const size_t MB = 1024 * 1024;
  unsigned short* Xb    = (unsigned short*)(ws);            // 4 MB  [0,4)
  unsigned short* Woeff = (unsigned short*)(ws + 4 * MB);   // 4 MB  [4,8)
  unsigned short* Weff  = (unsigned short*)(ws + 8 * MB);   // 12 MB [8,20)
  unsigned short* Qv    = (unsigned short*)(ws + 20 * MB);  // 8 MB  [20,28)
  unsigned short* Kv    = (unsigned short*)(ws + 28 * MB);  // 8 MB  [28,36)
  unsigned short* Vt    = (unsigned short*)(ws + 36 * MB);  // 8 MB  [36,44)
  // Weff dead after QKV GEMM; reuse:
  unsigned short* Aov   = (unsigned short*)(ws + 8 * MB);   // 8 MB  [8,16)

  cast_f32_bf16<<<dim3(1024), dim3(256), 0, stream>>>(x, Xb, (B_ * S_ * HID_) / 4);
  weff_kernel<<<dim3(64, 3), dim3(256), 0, stream>>>(Wq, Wk, Wv, aq, ak, av, Weff);
  qkv_gemm256<<<dim3(8, 8, 3), dim3(512), 0, stream>>>(Xb, Weff, Qv, Kv, Vt);
  attn_kernel<<<dim3(32, 32), dim3(256), 0, stream>>>(Qv, Kv, Vt, Aov);
  woeff_kernel<<<dim3(1024), dim3(256), 0, stream>>>(Wo, coll, Woeff);
  gemm64p<<<dim3(32, 16), dim3(256), 0, stream>>>(Aov, Woeff, out);
}

// Round 8
// 194.939 us; speedup vs baseline: 1.3482x; 1.3114x over previous
//
#include <hip/hip_runtime.h>
#include <hip/hip_bf16.h>

// Problem constants
#define B_    2
#define S_    1024
#define HID_  1024
#define H_    16
#define P_    2
#define D_    64
#define SV_   2048   // S_*P_
#define NBH_  32     // B_*H_
// SCALE * log2(e) = 0.125 * 1.4426950408889634
#define SCALE_LOG2E 0.18033688f

typedef __attribute__((ext_vector_type(8))) short short8;
typedef __attribute__((ext_vector_type(4))) short short4b;
typedef __attribute__((ext_vector_type(4))) float f32x4;

#if __has_builtin(__builtin_amdgcn_exp2f)
#define EXP2(x) __builtin_amdgcn_exp2f(x)
#else
#define EXP2(x) exp2f(x)
#endif

__device__ __forceinline__ unsigned short f2bf(float f) {
  union { float f; unsigned u; } v; v.f = f;
  unsigned r = v.u + 0x7fffu + ((v.u >> 16) & 1u);
  return (unsigned short)(r >> 16);
}
__device__ __forceinline__ unsigned pack_bf2(float a, float b) {
  __hip_bfloat162 h = __float22bfloat162_rn(make_float2(a, b));
  unsigned u; __builtin_memcpy(&u, &h, 4);
  return u;
}

// ---------------------------------------------------------------------------
__global__ __launch_bounds__(256) void cast_f32_bf16(
    const float* __restrict__ src, unsigned short* __restrict__ dst, int n4) {
  int i = blockIdx.x * blockDim.x + threadIdx.x;
  int stride = gridDim.x * blockDim.x;
  for (; i < n4; i += stride) {
    float4 v = ((const float4*)src)[i];
    ushort4 o;
    o.x = f2bf(v.x); o.y = f2bf(v.y); o.z = f2bf(v.z); o.w = f2bf(v.w);
    ((ushort4*)dst)[i] = o;
  }
}

// ---------------------------------------------------------------------------
// Weff[t][r=(h*128+p*64+d)][e] = sum_m A[m*32+hp] * W[m*64+d][e]
__global__ __launch_bounds__(256) void weff_kernel(
    const float* __restrict__ Wq, const float* __restrict__ Wk,
    const float* __restrict__ Wv,
    const float* __restrict__ aq, const float* __restrict__ ak,
    const float* __restrict__ av,
    unsigned short* __restrict__ Weff) {
  __shared__ float Al[16][32];
  const int d = blockIdx.x;   // 0..63
  const int t = blockIdx.y;   // 0..2
  const float* W = (t == 0) ? Wq : ((t == 1) ? Wk : Wv);
  const float* A = (t == 0) ? aq : ((t == 1) ? ak : av);
  const int tid = threadIdx.x;
  for (int idx = tid; idx < 512; idx += 256) Al[idx >> 5][idx & 31] = A[idx];
  __syncthreads();
  const int e = tid * 4;
  float wr[16][4];
#pragma unroll
  for (int m = 0; m < 16; ++m) {
    float4 v = *(const float4*)(W + (size_t)(m * 64 + d) * 1024 + e);
    wr[m][0] = v.x; wr[m][1] = v.y; wr[m][2] = v.z; wr[m][3] = v.w;
  }
  for (int hp = 0; hp < 32; ++hp) {
    float acc0 = 0.f, acc1 = 0.f, acc2 = 0.f, acc3 = 0.f;
#pragma unroll
    for (int m = 0; m < 16; ++m) {
      float al = Al[m][hp];
      acc0 += al * wr[m][0]; acc1 += al * wr[m][1];
      acc2 += al * wr[m][2]; acc3 += al * wr[m][3];
    }
    int r = (hp >> 1) * 128 + (hp & 1) * 64 + d;
    ushort4 ov;
    ov.x = f2bf(acc0); ov.y = f2bf(acc1); ov.z = f2bf(acc2); ov.w = f2bf(acc3);
    *(ushort4*)(Weff + ((size_t)t * 2048 + r) * 1024 + e) = ov;
  }
}

// ---------------------------------------------------------------------------
// Woeff[f][o*64+d] = sum_h coll[h*32+o] * Wo[f][h*64+d]   (bf16 out)
__global__ __launch_bounds__(256) void woeff_kernel(
    const float* __restrict__ Wo, const float* __restrict__ coll,
    unsigned short* __restrict__ Woeff) {
  __shared__ float wrow[1024];
  __shared__ float cl[512];
  const int f = blockIdx.x;
  const int tid = threadIdx.x;
  for (int idx = tid; idx < 512; idx += 256) cl[idx] = coll[idx];
  for (int idx = tid; idx < 1024; idx += 256) wrow[idx] = Wo[(size_t)f * 1024 + idx];
  __syncthreads();
  for (int idx = tid; idx < 2048; idx += 256) {
    int o = idx >> 6, d = idx & 63;
    float acc = 0.f;
#pragma unroll
    for (int h = 0; h < 16; ++h) acc += wrow[h * 64 + d] * cl[h * 32 + o];
    Woeff[(size_t)f * 2048 + idx] = f2bf(acc);
  }
}

// ---------------------------------------------------------------------------
// Unified QKV GEMM — 256x256-tile 8-phase schedule, DEPTH-2.5 PIPELINE.
// (unchanged; Q output pre-scaled by SCALE_LOG2E)
__global__ __launch_bounds__(512) void qkv_gemm256(
    const unsigned short* __restrict__ Xb,
    const unsigned short* __restrict__ Weff,
    unsigned short* __restrict__ Qd, unsigned short* __restrict__ Kd,
    unsigned short* __restrict__ Vd) {
  __shared__ unsigned short As[3][256 * 64];   // 96 KiB
  __shared__ unsigned short Bs[2][256 * 64];   // 64 KiB  -> 160 KiB total
  constexpr int K = 1024;
  constexpr int NT = 16;                        // K / 64
  const int t = threadIdx.x;
  const int wave = t >> 6, lane = t & 63, lrow = lane & 15, quad = lane >> 4;
  const int wm = wave >> 2, wn = wave & 3;      // 2M x 4N wave grid
  const int z = blockIdx.z;
  const int row0 = blockIdx.x * 256, col0 = blockIdx.y * 256;
  const unsigned short* Ap = (z == 2) ? (Weff + (size_t)2 * 2048 * 1024) : Xb;
  const unsigned short* Bp = (z == 2) ? Xb : (Weff + (size_t)z * 2048 * 1024);

  const int srow8 = lane >> 3;                 // row within the 8-row chunk
  const int sslot = (lane & 7) ^ srow8;        // pre-swizzled global 16B slot

  auto stageHT = [&](const unsigned short* __restrict__ gsrc,
                     unsigned short* __restrict__ ldsbase,
                     int half, int kt, int trow0) {
#pragma unroll
    for (int j = 0; j < 2; ++j) {
      const int rloc = half * 128 + wave * 16 + j * 8;  // wave-uniform
      const unsigned short* g =
          gsrc + (size_t)(trow0 + rloc + srow8) * K + kt * 64 + sslot * 8;
      __builtin_amdgcn_global_load_lds(
          (const __attribute__((address_space(1))) unsigned int*)g,
          (__attribute__((address_space(3))) unsigned int*)(ldsbase + rloc * 64),
          16, 0, 0);
    }
  };

  f32x4 acc[8][4];
#pragma unroll
  for (int mi = 0; mi < 8; ++mi)
#pragma unroll
    for (int ni = 0; ni < 4; ++ni) acc[mi][ni] = (f32x4){0.f, 0.f, 0.f, 0.f};

  stageHT(Ap, &As[0][0], 0, 0, row0);
  stageHT(Ap, &As[0][0], 1, 0, row0);
  stageHT(Bp, &Bs[0][0], 0, 0, col0);
  stageHT(Bp, &Bs[0][0], 1, 0, col0);
  stageHT(Ap, &As[1][0], 0, 1, row0);
  stageHT(Ap, &As[1][0], 1, 1, row0);
  stageHT(Bp, &Bs[1][0], 0, 1, col0);
  stageHT(Bp, &Bs[1][0], 1, 1, col0);
  asm volatile("s_waitcnt vmcnt(8)" ::: "memory");
  asm volatile("s_barrier" ::: "memory");

  const int swz = lrow & 7;

#define LDA(mi, ks)                                                         \
  (*(const short8*)(Ab + (wm * 128 + (mi)*16 + lrow) * 64 +                 \
                    ((((ks)*4 + quad) ^ swz) * 8)))

#define MFMA_PAIR(mA, mB, a00, a01, a10, a11)                               \
  _Pragma("unroll") for (int ni = 0; ni < 4; ++ni) {                        \
    acc[mA][ni] = __builtin_amdgcn_mfma_f32_16x16x32_bf16(                  \
        a00, bfrag[ni][0], acc[mA][ni], 0, 0, 0);                           \
    acc[mA][ni] = __builtin_amdgcn_mfma_f32_16x16x32_bf16(                  \
        a01, bfrag[ni][1], acc[mA][ni], 0, 0, 0);                           \
    acc[mB][ni] = __builtin_amdgcn_mfma_f32_16x16x32_bf16(                  \
        a10, bfrag[ni][0], acc[mB][ni], 0, 0, 0);                           \
    acc[mB][ni] = __builtin_amdgcn_mfma_f32_16x16x32_bf16(                  \
        a11, bfrag[ni][1], acc[mB][ni], 0, 0, 0);                           \
  }

  for (int kt = 0; kt < NT; ++kt) {
    const int abuf = kt % 3;
    const int anext = (kt + 2) % 3;
    const int bbuf = kt & 1;
    const bool pf = (kt + 2 < NT);
    const unsigned short* __restrict__ Ab = &As[abuf][0];
    const unsigned short* __restrict__ Bb = &Bs[bbuf][0];

    short8 bfrag[4][2];
    {
#pragma unroll
      for (int ni = 0; ni < 4; ++ni) {
        const int R = wn * 64 + ni * 16 + lrow;
#pragma unroll
        for (int ks = 0; ks < 2; ++ks)
          bfrag[ni][ks] =
              *(const short8*)(Bb + R * 64 + (((ks * 4 + quad) ^ swz) * 8));
      }
      short8 a00 = LDA(0, 0), a01 = LDA(0, 1), a10 = LDA(1, 0), a11 = LDA(1, 1);
      if (pf) stageHT(Ap, &As[anext][0], 0, kt + 2, row0);
      asm volatile("s_barrier" ::: "memory");
      asm volatile("s_waitcnt lgkmcnt(0)" ::: "memory");
      __builtin_amdgcn_s_setprio(1);
      MFMA_PAIR(0, 1, a00, a01, a10, a11)
      __builtin_amdgcn_s_setprio(0);
      asm volatile("s_barrier" ::: "memory");
    }
    {
      short8 a00 = LDA(2, 0), a01 = LDA(2, 1), a10 = LDA(3, 0), a11 = LDA(3, 1);
      if (pf) stageHT(Ap, &As[anext][0], 1, kt + 2, row0);
      asm volatile("s_barrier" ::: "memory");
      asm volatile("s_waitcnt lgkmcnt(0)" ::: "memory");
      __builtin_amdgcn_s_setprio(1);
      MFMA_PAIR(2, 3, a00, a01, a10, a11)
      __builtin_amdgcn_s_setprio(0);
      asm volatile("s_barrier" ::: "memory");
    }
    {
      short8 a00 = LDA(4, 0), a01 = LDA(4, 1), a10 = LDA(5, 0), a11 = LDA(5, 1);
      if (pf) stageHT(Bp, &Bs[bbuf][0], 0, kt + 2, col0);
      asm volatile("s_barrier" ::: "memory");
      asm volatile("s_waitcnt lgkmcnt(0)" ::: "memory");
      __builtin_amdgcn_s_setprio(1);
      MFMA_PAIR(4, 5, a00, a01, a10, a11)
      __builtin_amdgcn_s_setprio(0);
      asm volatile("s_barrier" ::: "memory");
    }
    {
      short8 a00 = LDA(6, 0), a01 = LDA(6, 1), a10 = LDA(7, 0), a11 = LDA(7, 1);
      if (pf) stageHT(Bp, &Bs[bbuf][0], 1, kt + 2, col0);
      asm volatile("s_barrier" ::: "memory");
      asm volatile("s_waitcnt lgkmcnt(0)" ::: "memory");
      __builtin_amdgcn_s_setprio(1);
      MFMA_PAIR(6, 7, a00, a01, a10, a11)
      __builtin_amdgcn_s_setprio(0);
      if (pf) {
        asm volatile("s_waitcnt vmcnt(8)" ::: "memory");
      } else {
        asm volatile("s_waitcnt vmcnt(0)" ::: "memory");
      }
      asm volatile("s_barrier" ::: "memory");
    }
  }
#undef LDA
#undef MFMA_PAIR

#pragma unroll
  for (int mi = 0; mi < 8; ++mi) {
#pragma unroll
    for (int ni = 0; ni < 4; ++ni) {
#pragma unroll
      for (int i = 0; i < 4; ++i) {
        int grow = row0 + wm * 128 + mi * 16 + quad * 4 + i;
        int gcol = col0 + wn * 64 + ni * 16 + lrow;
        float val = acc[mi][ni][i];
        if (z != 2) {
          if (z == 0) val *= SCALE_LOG2E;  // pre-scale Q for exp2-direct attn
          int b = grow >> 10, n = grow & 1023;
          int h = gcol >> 7, p = (gcol >> 6) & 1, d = gcol & 63;
          unsigned short* dst = (z == 0) ? Qd : Kd;
          dst[((size_t)((b * 16 + h) * 2048) + n * 2 + p) * 64 + d] = f2bf(val);
        } else {
          int h = grow >> 7, p = (grow >> 6) & 1, d = grow & 63;
          int b = gcol >> 10, n = gcol & 1023;
          Vd[((size_t)((b * 16 + h) * 64 + d)) * 2048 + n * 2 + p] = f2bf(val);
        }
      }
    }
  }
}

// ---------------------------------------------------------------------------
// Output GEMM, depth-2 pipeline: 64x64 tile, BK=64, TRIPLE-buffered A/B,
// ONE barrier + counted vmcnt(4) per K-tile. Grid (32,16) = 2 blocks/CU.
__global__ __launch_bounds__(256) void gemm64p(
    const unsigned short* __restrict__ A,      // [2048 x 2048] row-major
    const unsigned short* __restrict__ Bbase,  // [1024 x 2048] (B^T form)
    float* __restrict__ Cf) {                  // [2048 x 1024]
  __shared__ unsigned short As[3][64 * 64];    // 24 KB
  __shared__ unsigned short Bs[3][64 * 64];    // 24 KB
  constexpr int K = 2048, N = 1024, NT = 32;   // K / 64
  const int t = threadIdx.x;
  const int wave = t >> 6, lane = t & 63, lrow = lane & 15, quad = lane >> 4;
  const int wm = wave >> 1, wn = wave & 1;     // 2x2 wave grid, 32x32 each
  const int row0 = blockIdx.x * 64, col0 = blockIdx.y * 64;
  const int srow8 = lane >> 3;
  const int sslot = (lane & 7) ^ srow8;        // pre-swizzled global slot
  const int swz = lrow & 7;

  auto stage = [&](int kt, int buf) {
#pragma unroll
    for (int j = 0; j < 2; ++j) {
      const int rloc = wave * 16 + j * 8;
      const unsigned short* ga =
          A + (size_t)(row0 + rloc + srow8) * K + kt * 64 + sslot * 8;
      __builtin_amdgcn_global_load_lds(
          (const __attribute__((address_space(1))) unsigned int*)ga,
          (__attribute__((address_space(3))) unsigned int*)(&As[buf][rloc * 64]),
          16, 0, 0);
      const unsigned short* gb =
          Bbase + (size_t)(col0 + rloc + srow8) * K + kt * 64 + sslot * 8;
      __builtin_amdgcn_global_load_lds(
          (const __attribute__((address_space(1))) unsigned int*)gb,
          (__attribute__((address_space(3))) unsigned int*)(&Bs[buf][rloc * 64]),
          16, 0, 0);
    }
  };

  f32x4 acc[2][2];
#pragma unroll
  for (int mi = 0; mi < 2; ++mi)
#pragma unroll
    for (int ni = 0; ni < 2; ++ni) acc[mi][ni] = (f32x4){0.f, 0.f, 0.f, 0.f};

  stage(0, 0);
  stage(1, 1);

  for (int kt = 0; kt < NT; ++kt) {
    const int buf = kt % 3;
    if (kt < NT - 1) {
      asm volatile("s_waitcnt vmcnt(4)" ::: "memory");  // tile kt landed
    } else {
      asm volatile("s_waitcnt vmcnt(0)" ::: "memory");
    }
    asm volatile("s_barrier" ::: "memory");
    if (kt + 2 < NT) stage(kt + 2, (kt + 2) % 3);

    const unsigned short* __restrict__ Ab = &As[buf][0];
    const unsigned short* __restrict__ Bb = &Bs[buf][0];
    short8 af[2][2], bf[2][2];
#pragma unroll
    for (int mi = 0; mi < 2; ++mi)
#pragma unroll
      for (int ks = 0; ks < 2; ++ks)
        af[mi][ks] = *(const short8*)(
            Ab + (wm * 32 + mi * 16 + lrow) * 64 + (((ks * 4 + quad) ^ swz) * 8));
#pragma unroll
    for (int ni = 0; ni < 2; ++ni)
#pragma unroll
      for (int ks = 0; ks < 2; ++ks)
        bf[ni][ks] = *(const short8*)(
            Bb + (wn * 32 + ni * 16 + lrow) * 64 + (((ks * 4 + quad) ^ swz) * 8));
    __builtin_amdgcn_s_setprio(1);
#pragma unroll
    for (int mi = 0; mi < 2; ++mi)
#pragma unroll
      for (int ni = 0; ni < 2; ++ni) {
        acc[mi][ni] = __builtin_amdgcn_mfma_f32_16x16x32_bf16(
            af[mi][0], bf[ni][0], acc[mi][ni], 0, 0, 0);
        acc[mi][ni] = __builtin_amdgcn_mfma_f32_16x16x32_bf16(
            af[mi][1], bf[ni][1], acc[mi][ni], 0, 0, 0);
      }
    __builtin_amdgcn_s_setprio(0);
  }

#pragma unroll
  for (int mi = 0; mi < 2; ++mi)
#pragma unroll
    for (int ni = 0; ni < 2; ++ni)
#pragma unroll
      for (int i = 0; i < 4; ++i) {
        int grow = row0 + wm * 32 + mi * 16 + quad * 4 + i;
        int gcol = col0 + wn * 32 + ni * 16 + lrow;
        Cf[(size_t)grow * N + gcol] = acc[mi][ni][i];
      }
}

// ---------------------------------------------------------------------------
// Causal flash attention v6: round-3 structure (global_load_lds staging,
// KVBLK=64, in-register P via 16x16x16 PV MFMA, Q pre-scaled) but with
// TRIPLE-buffered K/V (3 x 16 KB = 48 KB LDS -> 3 blocks/CU) and ONE
// barrier + ONE counted vmcnt per tile (gemm64p trick): at iter kt the
// overwrite target is buf (kt+2)%3 = (kt-1)%3 whose readers all passed
// this iteration's barrier. Stage is issued after the barrier -> ~2
// iterations of DMA flight. No register staging (v4/v5 scratch-spill
// lesson: reg-staging blocks spill across asm barriers on this compiler).
__global__ __launch_bounds__(256, 3) void attn_kernel(
    const unsigned short* __restrict__ Qv, const unsigned short* __restrict__ Kv,
    const unsigned short* __restrict__ Vt, unsigned short* __restrict__ Aov) {
  __shared__ unsigned short Ks[3][4096];   // [buf][row 64][col 64] swizzled
  __shared__ unsigned short Vs[3][4096];   // [buf][d 64][kcol 64] swizzled
  const int bh = blockIdx.x;
  const int yy = blockIdx.y;
  const int qt = (yy < 16) ? yy : (47 - yy);
  const int t = threadIdx.x;
  const int w = t >> 6, lane = t & 63, lq = lane & 15, quad = lane >> 4;
  const int l3 = lq & 7;

  const unsigned short* Qh = Qv + (size_t)bh * SV_ * D_;
  const unsigned short* Kh = Kv + (size_t)bh * SV_ * D_;
  const unsigned short* Vh = Vt + (size_t)bh * D_ * SV_;

  const int qrow = qt * 64 + w * 16 + lq;  // this lane's q row
  short8 bq0 = *(const short8*)(Qh + (size_t)qrow * 64 + quad * 8);
  short8 bq1 = *(const short8*)(Qh + (size_t)qrow * 64 + 32 + quad * 8);

  // Staging: lane-linear LDS granules; global side applies the XOR swizzle.
  const int sg = (lane & 7) ^ ((lane >> 3) & 7);  // granule ^ (row&7)
  const int r0 = w * 16 + (lane >> 3);            // row for issue 0 (+8 for issue 1)
  const unsigned short* Kg0 = Kh + r0 * 64 + sg * 8;
  const unsigned short* Vg0 = Vh + (size_t)r0 * SV_ + sg * 8;
  const int lds0 = w * 1024;       // shorts (16 rows x 64), wave-uniform
  const int lds1 = lds0 + 512;     // +8 rows

  auto stage = [&](int kt) {
    const int buf = kt % 3;
    const unsigned short* kg = Kg0 + kt * 4096;
    const unsigned short* vg = Vg0 + kt * 64;
    __builtin_amdgcn_global_load_lds(
        (const __attribute__((address_space(1))) unsigned int*)kg,
        (__attribute__((address_space(3))) unsigned int*)(&Ks[buf][lds0]), 16, 0, 0);
    __builtin_amdgcn_global_load_lds(
        (const __attribute__((address_space(1))) unsigned int*)(kg + 8 * 64),
        (__attribute__((address_space(3))) unsigned int*)(&Ks[buf][lds1]), 16, 0, 0);
    __builtin_amdgcn_global_load_lds(
        (const __attribute__((address_space(1))) unsigned int*)vg,
        (__attribute__((address_space(3))) unsigned int*)(&Vs[buf][lds0]), 16, 0, 0);
    __builtin_amdgcn_global_load_lds(
        (const __attribute__((address_space(1))) unsigned int*)(vg + (size_t)8 * SV_),
        (__attribute__((address_space(3))) unsigned int*)(&Vs[buf][lds1]), 16, 0, 0);
  };

  float l_sum = 0.f;
  f32x4 o_acc[4];
#pragma unroll
  for (int nd = 0; nd < 4; ++nd) o_acc[nd] = (f32x4){0.f, 0.f, 0.f, 0.f};

  const int nt = qt + 1;
  stage(0);
  if (nt > 1) stage(1);

  for (int kt = 0; kt < nt; ++kt) {
    const int buf = kt % 3;
    // own tile-kt loads landed (leave tile kt+1's 4 in flight if any)
    if (kt + 1 < nt) {
      asm volatile("s_waitcnt vmcnt(4)" ::: "memory");
    } else {
      asm volatile("s_waitcnt vmcnt(0)" ::: "memory");
    }
    // single barrier: publishes all waves' tile-kt DMA, retires kt-1 reads
    asm volatile("s_barrier" ::: "memory");
    if (kt + 2 < nt) stage(kt + 2);   // overwrites buf (kt-1)%3: safe now

    // ---- K fragments from LDS ----
    const unsigned short* Kb = Ks[buf];
    short8 ka[4][2];
#pragma unroll
    for (int t4 = 0; t4 < 4; ++t4)
#pragma unroll
      for (int c = 0; c < 2; ++c)
        ka[t4][c] = *(const short8*)(Kb + (t4 * 16 + lq) * 64 + (((c * 4 + quad) ^ l3) * 8));

    // ---- S^T = K·Q^T (Q pre-scaled by SCALE*log2e) ----
    f32x4 s[4];
#pragma unroll
    for (int t4 = 0; t4 < 4; ++t4) {
      f32x4 z = (f32x4){0.f, 0.f, 0.f, 0.f};
      z = __builtin_amdgcn_mfma_f32_16x16x32_bf16(ka[t4][0], bq0, z, 0, 0, 0);
      s[t4] = __builtin_amdgcn_mfma_f32_16x16x32_bf16(ka[t4][1], bq1, z, 0, 0, 0);
    }

    // ---- p = exp2(s), diagonal mask, in-lane row-sum, in-register PV ----
    const bool diag = (kt == qt);
    const int kc0 = kt * 64 + quad * 4;
    const unsigned short* Vb = Vs[buf];
    float rs = 0.f;
    __builtin_amdgcn_s_setprio(1);
#pragma unroll
    for (int t4 = 0; t4 < 4; ++t4) {
      float p0 = EXP2(s[t4][0]), p1 = EXP2(s[t4][1]);
      float p2 = EXP2(s[t4][2]), p3 = EXP2(s[t4][3]);
      if (diag) {
        const int kc = kc0 + t4 * 16;
        if (kc + 0 > qrow) p0 = 0.f;
        if (kc + 1 > qrow) p1 = 0.f;
        if (kc + 2 > qrow) p2 = 0.f;
        if (kc + 3 > qrow) p3 = 0.f;
      }
      rs += (p0 + p1) + (p2 + p3);
      // P fragment for mfma_16x16x16 B-operand: lane(lq,quad) holds
      // B[k=quad*4+j][col=lq] == p[j]. No LDS roundtrip.
      unsigned ww[2];
      ww[0] = pack_bf2(p0, p1);
      ww[1] = pack_bf2(p2, p3);
      short4b pb;
      __builtin_memcpy(&pb, ww, 8);
      // V^T fragment: A[row=lq][k=quad*4+j] = V^T[nd*16+lq][t4*16+quad*4+j]
      const int cg = t4 * 2 + (quad >> 1);
      const int vcol = ((cg ^ l3) * 8) + (quad & 1) * 4;
#pragma unroll
      for (int nd = 0; nd < 4; ++nd) {
        short4b va4;
        __builtin_memcpy(&va4, Vb + (nd * 16 + lq) * 64 + vcol, 8);
        o_acc[nd] = __builtin_amdgcn_mfma_f32_16x16x16bf16_1k(va4, pb,
                                                              o_acc[nd], 0, 0, 0);
      }
    }
    __builtin_amdgcn_s_setprio(0);
    l_sum += rs;
  }

  // final cross-quad row-sum reduction
  l_sum += __shfl_xor(l_sum, 16);
  l_sum += __shfl_xor(l_sum, 32);

  const int b = bh >> 4, h = bh & 15;
  const float inv = 1.0f / l_sum;
  const int n = qrow >> 1, p = qrow & 1;
  unsigned short* dst = Aov + ((size_t)(b * 1024 + n)) * 2048 + (h * 2 + p) * 64;
#pragma unroll
  for (int nd = 0; nd < 4; ++nd) {
    uint2 dw;
    dw.x = pack_bf2(o_acc[nd][0] * inv, o_acc[nd][1] * inv);
    dw.y = pack_bf2(o_acc[nd][2] * inv, o_acc[nd][3] * inv);
    *(uint2*)(dst + nd * 16 + quad * 4) = dw;
  }
}

// ---------------------------------------------------------------------------
extern "C" void kernel_launch(void* const* d_in, const int* in_sizes, int n_in,
                              void* d_out, int out_size, void* d_ws, size_t ws_size,
                              hipStream_t stream) {
  (void)in_sizes; (void)n_in; (void)out_size; (void)ws_size;
  const float* x    = (const float*)d_in[0];
  const float* Wq   = (const float*)d_in[1];
  const float* Wk   = (const float*)d_in[2];
  const float* Wv   = (const float*)d_in[3];
  const float* Wo   = (const float*)d_in[4];
  const float* aq   = (const float*)d_in[5];
  const float* ak   = (const float*)d_in[6];
  const float* av   = (const float*)d_in[7];
  const float* coll = (const float*)d_in[8];
  float* out = (float*)d_out;

  char* ws = (char*)d_ws;
  const size_t MB = 1024 * 1024;
  unsigned short* Xb    = (unsigned short*)(ws);            // 4 MB  [0,4)
  unsigned short* Woeff = (unsigned short*)(ws + 4 * MB);   // 4 MB  [4,8)
  unsigned short* Weff  = (unsigned short*)(ws + 8 * MB);   // 12 MB [8,20)
  unsigned short* Qv    = (unsigned short*)(ws + 20 * MB);  // 8 MB  [20,28)
  unsigned short* Kv    = (unsigned short*)(ws + 28 * MB);  // 8 MB  [28,36)
  unsigned short* Vt    = (unsigned short*)(ws + 36 * MB);  // 8 MB  [36,44)
  // Weff dead after QKV GEMM; reuse:
  unsigned short* Aov   = (unsigned short*)(ws + 8 * MB);   // 8 MB  [8,16)

  cast_f32_bf16<<<dim3(1024), dim3(256), 0, stream>>>(x, Xb, (B_ * S_ * HID_) / 4);
  weff_kernel<<<dim3(64, 3), dim3(256), 0, stream>>>(Wq, Wk, Wv, aq, ak, av, Weff);
  qkv_gemm256<<<dim3(8, 8, 3), dim3(512), 0, stream>>>(Xb, Weff, Qv, Kv, Vt);
  attn_kernel<<<dim3(32, 32), dim3(256), 0, stream>>>(Qv, Kv, Vt, Aov);
  woeff_kernel<<<dim3(1024), dim3(256), 0, stream>>>(Wo, coll, Woeff);
  gemm64p<<<dim3(32, 16), dim3(256), 0, stream>>>(Aov, Woeff, out);
}

// Round 10
// 190.521 us; speedup vs baseline: 1.3794x; 1.0232x over previous
//
#include <hip/hip_runtime.h>
#include <hip/hip_bf16.h>

// Problem constants
#define B_    2
#define S_    1024
#define HID_  1024
#define H_    16
#define P_    2
#define D_    64
#define SV_   2048   // S_*P_
#define NBH_  32     // B_*H_
// SCALE * log2(e) = 0.125 * 1.4426950408889634
#define SCALE_LOG2E 0.18033688f

typedef __attribute__((ext_vector_type(8))) short short8;
typedef __attribute__((ext_vector_type(4))) short short4b;
typedef __attribute__((ext_vector_type(4))) float f32x4;

#if __has_builtin(__builtin_amdgcn_exp2f)
#define EXP2(x) __builtin_amdgcn_exp2f(x)
#else
#define EXP2(x) exp2f(x)
#endif

__device__ __forceinline__ unsigned short f2bf(float f) {
  union { float f; unsigned u; } v; v.f = f;
  unsigned r = v.u + 0x7fffu + ((v.u >> 16) & 1u);
  return (unsigned short)(r >> 16);
}
__device__ __forceinline__ unsigned pack_bf2(float a, float b) {
  __hip_bfloat162 h = __float22bfloat162_rn(make_float2(a, b));
  unsigned u; __builtin_memcpy(&u, &h, 4);
  return u;
}

// ---------------------------------------------------------------------------
__global__ __launch_bounds__(256) void cast_f32_bf16(
    const float* __restrict__ src, unsigned short* __restrict__ dst, int n4) {
  int i = blockIdx.x * blockDim.x + threadIdx.x;
  int stride = gridDim.x * blockDim.x;
  for (; i < n4; i += stride) {
    float4 v = ((const float4*)src)[i];
    ushort4 o;
    o.x = f2bf(v.x); o.y = f2bf(v.y); o.z = f2bf(v.z); o.w = f2bf(v.w);
    ((ushort4*)dst)[i] = o;
  }
}

// ---------------------------------------------------------------------------
// Weff[t][r=(h*128+p*64+d)][e] = sum_m A[m*32+hp] * W[m*64+d][e]
__global__ __launch_bounds__(256) void weff_kernel(
    const float* __restrict__ Wq, const float* __restrict__ Wk,
    const float* __restrict__ Wv,
    const float* __restrict__ aq, const float* __restrict__ ak,
    const float* __restrict__ av,
    unsigned short* __restrict__ Weff) {
  __shared__ float Al[16][32];
  const int d = blockIdx.x;   // 0..63
  const int t = blockIdx.y;   // 0..2
  const float* W = (t == 0) ? Wq : ((t == 1) ? Wk : Wv);
  const float* A = (t == 0) ? aq : ((t == 1) ? ak : av);
  const int tid = threadIdx.x;
  for (int idx = tid; idx < 512; idx += 256) Al[idx >> 5][idx & 31] = A[idx];
  __syncthreads();
  const int e = tid * 4;
  float wr[16][4];
#pragma unroll
  for (int m = 0; m < 16; ++m) {
    float4 v = *(const float4*)(W + (size_t)(m * 64 + d) * 1024 + e);
    wr[m][0] = v.x; wr[m][1] = v.y; wr[m][2] = v.z; wr[m][3] = v.w;
  }
  for (int hp = 0; hp < 32; ++hp) {
    float acc0 = 0.f, acc1 = 0.f, acc2 = 0.f, acc3 = 0.f;
#pragma unroll
    for (int m = 0; m < 16; ++m) {
      float al = Al[m][hp];
      acc0 += al * wr[m][0]; acc1 += al * wr[m][1];
      acc2 += al * wr[m][2]; acc3 += al * wr[m][3];
    }
    int r = (hp >> 1) * 128 + (hp & 1) * 64 + d;
    ushort4 ov;
    ov.x = f2bf(acc0); ov.y = f2bf(acc1); ov.z = f2bf(acc2); ov.w = f2bf(acc3);
    *(ushort4*)(Weff + ((size_t)t * 2048 + r) * 1024 + e) = ov;
  }
}

// ---------------------------------------------------------------------------
// Woeff[f][o*64+d] = sum_h coll[h*32+o] * Wo[f][h*64+d]   (bf16 out)
__global__ __launch_bounds__(256) void woeff_kernel(
    const float* __restrict__ Wo, const float* __restrict__ coll,
    unsigned short* __restrict__ Woeff) {
  __shared__ float wrow[1024];
  __shared__ float cl[512];
  const int f = blockIdx.x;
  const int tid = threadIdx.x;
  for (int idx = tid; idx < 512; idx += 256) cl[idx] = coll[idx];
  for (int idx = tid; idx < 1024; idx += 256) wrow[idx] = Wo[(size_t)f * 1024 + idx];
  __syncthreads();
  for (int idx = tid; idx < 2048; idx += 256) {
    int o = idx >> 6, d = idx & 63;
    float acc = 0.f;
#pragma unroll
    for (int h = 0; h < 16; ++h) acc += wrow[h * 64 + d] * cl[h * 32 + o];
    Woeff[(size_t)f * 2048 + idx] = f2bf(acc);
  }
}

// ---------------------------------------------------------------------------
// Unified QKV GEMM v2 — 128x128 tile, BK=32, TRIPLE-buffered (48 KB LDS ->
// 3 blocks/CU), ONE barrier + ONE counted vmcnt(4) per K-tile, depth-2
// prefetch (stage kt+2 after the barrier -> ~2 iterations of DMA flight).
// Grid (16,16,3) = 768 blocks = 3/CU (full 256-CU fill, 12 waves/CU TLP).
// XOR swizzle, BK=32 form: read granule quad^((lq>>1)&3); staged via
// pre-swizzled GLOBAL source granule (lane&3)^((lane>>3)&3), linear LDS.
// z=0: Q = Xb·Weff_q^T (pre-scaled by SCALE_LOG2E); z=1: K; z=2: V^T.
__global__ __launch_bounds__(256, 3) void qkv_gemm128(
    const unsigned short* __restrict__ Xb,
    const unsigned short* __restrict__ Weff,
    unsigned short* __restrict__ Qd, unsigned short* __restrict__ Kd,
    unsigned short* __restrict__ Vd) {
  __shared__ unsigned short As[3][128 * 32];   // 24 KB
  __shared__ unsigned short Bs[3][128 * 32];   // 24 KB
  constexpr int K = 1024, NT = 32;              // K / 32
  const int t = threadIdx.x;
  const int wave = t >> 6, lane = t & 63, lq = lane & 15, quad = lane >> 4;
  const int wm = wave >> 1, wn = wave & 1;      // 2x2 waves, 64x64 each
  const int z = blockIdx.z;
  const int row0 = blockIdx.x * 128, col0 = blockIdx.y * 128;
  const unsigned short* Ap = (z == 2) ? (Weff + (size_t)2 * 2048 * 1024) : Xb;
  const unsigned short* Bp = (z == 2) ? Xb : (Weff + (size_t)z * 2048 * 1024);

  // Staging: wave-load = 16 rows x 64B. lane -> row lane>>2, granule lane&3,
  // global granule pre-swizzled by row-within-chunk: ^ ((lane>>3)&3).
  const int srow = lane >> 2;                       // 0..15
  const int sgr = (lane & 3) ^ ((lane >> 3) & 3);   // pre-swizzled granule

  auto stage = [&](int kt, int buf) {
#pragma unroll
    for (int j = 0; j < 2; ++j) {
      const int rloc = wave * 32 + j * 16;  // wave-uniform chunk base row
      const unsigned short* ga =
          Ap + (size_t)(row0 + rloc + srow) * K + kt * 32 + sgr * 8;
      __builtin_amdgcn_global_load_lds(
          (const __attribute__((address_space(1))) unsigned int*)ga,
          (__attribute__((address_space(3))) unsigned int*)(&As[buf][rloc * 32]),
          16, 0, 0);
      const unsigned short* gb =
          Bp + (size_t)(col0 + rloc + srow) * K + kt * 32 + sgr * 8;
      __builtin_amdgcn_global_load_lds(
          (const __attribute__((address_space(1))) unsigned int*)gb,
          (__attribute__((address_space(3))) unsigned int*)(&Bs[buf][rloc * 32]),
          16, 0, 0);
    }
  };

  f32x4 acc[4][4];
#pragma unroll
  for (int mi = 0; mi < 4; ++mi)
#pragma unroll
    for (int ni = 0; ni < 4; ++ni) acc[mi][ni] = (f32x4){0.f, 0.f, 0.f, 0.f};

  stage(0, 0);
  stage(1, 1);

  const int swz4 = (lq >> 1) & 3;   // read-side granule XOR

  for (int kt = 0; kt < NT; ++kt) {
    const int buf = kt % 3;
    // own tile-kt loads landed; tile kt+1's 4 stay in flight
    if (kt + 1 < NT) {
      asm volatile("s_waitcnt vmcnt(4)" ::: "memory");
    } else {
      asm volatile("s_waitcnt vmcnt(0)" ::: "memory");
    }
    // single barrier: publishes tile-kt DMA, retires tile-(kt-1) reads
    asm volatile("s_barrier" ::: "memory");
    if (kt + 2 < NT) stage(kt + 2, (kt + 2) % 3);  // overwrites (kt-1)%3

    const unsigned short* __restrict__ Ab = &As[buf][0];
    const unsigned short* __restrict__ Bb = &Bs[buf][0];
    short8 af[4], bf[4];
#pragma unroll
    for (int mi = 0; mi < 4; ++mi)
      af[mi] = *(const short8*)(
          Ab + (wm * 64 + mi * 16 + lq) * 32 + ((quad ^ swz4) * 8));
#pragma unroll
    for (int ni = 0; ni < 4; ++ni)
      bf[ni] = *(const short8*)(
          Bb + (wn * 64 + ni * 16 + lq) * 32 + ((quad ^ swz4) * 8));
    __builtin_amdgcn_s_setprio(1);
#pragma unroll
    for (int mi = 0; mi < 4; ++mi)
#pragma unroll
      for (int ni = 0; ni < 4; ++ni)
        acc[mi][ni] = __builtin_amdgcn_mfma_f32_16x16x32_bf16(
            af[mi], bf[ni], acc[mi][ni], 0, 0, 0);
    __builtin_amdgcn_s_setprio(0);
  }

  // Epilogue: scattered bf16 stores into head-interleaved layouts.
#pragma unroll
  for (int mi = 0; mi < 4; ++mi) {
#pragma unroll
    for (int ni = 0; ni < 4; ++ni) {
#pragma unroll
      for (int i = 0; i < 4; ++i) {
        int grow = row0 + wm * 64 + mi * 16 + quad * 4 + i;
        int gcol = col0 + wn * 64 + ni * 16 + lq;
        float val = acc[mi][ni][i];
        if (z != 2) {
          if (z == 0) val *= SCALE_LOG2E;  // pre-scale Q for exp2-direct attn
          int b = grow >> 10, n = grow & 1023;
          int h = gcol >> 7, p = (gcol >> 6) & 1, d = gcol & 63;
          unsigned short* dst = (z == 0) ? Qd : Kd;
          dst[((size_t)((b * 16 + h) * 2048) + n * 2 + p) * 64 + d] = f2bf(val);
        } else {
          // grow = (h,p,d), gcol = (b, n)
          int h = grow >> 7, p = (grow >> 6) & 1, d = grow & 63;
          int b = gcol >> 10, n = gcol & 1023;
          Vd[((size_t)((b * 16 + h) * 64 + d)) * 2048 + n * 2 + p] = f2bf(val);
        }
      }
    }
  }
}

// ---------------------------------------------------------------------------
// Output GEMM, depth-2 pipeline: 64x64 tile, BK=64, TRIPLE-buffered A/B,
// ONE barrier + counted vmcnt(4) per K-tile. Grid (32,16) = 2 blocks/CU.
__global__ __launch_bounds__(256) void gemm64p(
    const unsigned short* __restrict__ A,      // [2048 x 2048] row-major
    const unsigned short* __restrict__ Bbase,  // [1024 x 2048] (B^T form)
    float* __restrict__ Cf) {                  // [2048 x 1024]
  __shared__ unsigned short As[3][64 * 64];    // 24 KB
  __shared__ unsigned short Bs[3][64 * 64];    // 24 KB
  constexpr int K = 2048, N = 1024, NT = 32;   // K / 64
  const int t = threadIdx.x;
  const int wave = t >> 6, lane = t & 63, lrow = lane & 15, quad = lane >> 4;
  const int wm = wave >> 1, wn = wave & 1;     // 2x2 wave grid, 32x32 each
  const int row0 = blockIdx.x * 64, col0 = blockIdx.y * 64;
  const int srow8 = lane >> 3;
  const int sslot = (lane & 7) ^ srow8;        // pre-swizzled global slot
  const int swz = lrow & 7;

  auto stage = [&](int kt, int buf) {
#pragma unroll
    for (int j = 0; j < 2; ++j) {
      const int rloc = wave * 16 + j * 8;
      const unsigned short* ga =
          A + (size_t)(row0 + rloc + srow8) * K + kt * 64 + sslot * 8;
      __builtin_amdgcn_global_load_lds(
          (const __attribute__((address_space(1))) unsigned int*)ga,
          (__attribute__((address_space(3))) unsigned int*)(&As[buf][rloc * 64]),
          16, 0, 0);
      const unsigned short* gb =
          Bbase + (size_t)(col0 + rloc + srow8) * K + kt * 64 + sslot * 8;
      __builtin_amdgcn_global_load_lds(
          (const __attribute__((address_space(1))) unsigned int*)gb,
          (__attribute__((address_space(3))) unsigned int*)(&Bs[buf][rloc * 64]),
          16, 0, 0);
    }
  };

  f32x4 acc[2][2];
#pragma unroll
  for (int mi = 0; mi < 2; ++mi)
#pragma unroll
    for (int ni = 0; ni < 2; ++ni) acc[mi][ni] = (f32x4){0.f, 0.f, 0.f, 0.f};

  stage(0, 0);
  stage(1, 1);

  for (int kt = 0; kt < NT; ++kt) {
    const int buf = kt % 3;
    if (kt < NT - 1) {
      asm volatile("s_waitcnt vmcnt(4)" ::: "memory");  // tile kt landed
    } else {
      asm volatile("s_waitcnt vmcnt(0)" ::: "memory");
    }
    asm volatile("s_barrier" ::: "memory");
    if (kt + 2 < NT) stage(kt + 2, (kt + 2) % 3);

    const unsigned short* __restrict__ Ab = &As[buf][0];
    const unsigned short* __restrict__ Bb = &Bs[buf][0];
    short8 af[2][2], bf[2][2];
#pragma unroll
    for (int mi = 0; mi < 2; ++mi)
#pragma unroll
      for (int ks = 0; ks < 2; ++ks)
        af[mi][ks] = *(const short8*)(
            Ab + (wm * 32 + mi * 16 + lrow) * 64 + (((ks * 4 + quad) ^ swz) * 8));
#pragma unroll
    for (int ni = 0; ni < 2; ++ni)
#pragma unroll
      for (int ks = 0; ks < 2; ++ks)
        bf[ni][ks] = *(const short8*)(
            Bb + (wn * 32 + ni * 16 + lrow) * 64 + (((ks * 4 + quad) ^ swz) * 8));
    __builtin_amdgcn_s_setprio(1);
#pragma unroll
    for (int mi = 0; mi < 2; ++mi)
#pragma unroll
      for (int ni = 0; ni < 2; ++ni) {
        acc[mi][ni] = __builtin_amdgcn_mfma_f32_16x16x32_bf16(
            af[mi][0], bf[ni][0], acc[mi][ni], 0, 0, 0);
        acc[mi][ni] = __builtin_amdgcn_mfma_f32_16x16x32_bf16(
            af[mi][1], bf[ni][1], acc[mi][ni], 0, 0, 0);
      }
    __builtin_amdgcn_s_setprio(0);
  }

#pragma unroll
  for (int mi = 0; mi < 2; ++mi)
#pragma unroll
    for (int ni = 0; ni < 2; ++ni)
#pragma unroll
      for (int i = 0; i < 4; ++i) {
        int grow = row0 + wm * 32 + mi * 16 + quad * 4 + i;
        int gcol = col0 + wn * 32 + ni * 16 + lrow;
        Cf[(size_t)grow * N + gcol] = acc[mi][ni][i];
      }
}

// ---------------------------------------------------------------------------
// Causal flash attention v6: global_load_lds staging, KVBLK=64,
// TRIPLE-buffered K/V (48 KB -> 3 blocks/CU), ONE barrier + ONE counted
// vmcnt per tile, in-register P via 16x16x16 MFMA, Q pre-scaled.
__global__ __launch_bounds__(256, 3) void attn_kernel(
    const unsigned short* __restrict__ Qv, const unsigned short* __restrict__ Kv,
    const unsigned short* __restrict__ Vt, unsigned short* __restrict__ Aov) {
  __shared__ unsigned short Ks[3][4096];   // [buf][row 64][col 64] swizzled
  __shared__ unsigned short Vs[3][4096];   // [buf][d 64][kcol 64] swizzled
  const int bh = blockIdx.x;
  const int yy = blockIdx.y;
  const int qt = (yy < 16) ? yy : (47 - yy);
  const int t = threadIdx.x;
  const int w = t >> 6, lane = t & 63, lq = lane & 15, quad = lane >> 4;
  const int l3 = lq & 7;

  const unsigned short* Qh = Qv + (size_t)bh * SV_ * D_;
  const unsigned short* Kh = Kv + (size_t)bh * SV_ * D_;
  const unsigned short* Vh = Vt + (size_t)bh * D_ * SV_;

  const int qrow = qt * 64 + w * 16 + lq;  // this lane's q row
  short8 bq0 = *(const short8*)(Qh + (size_t)qrow * 64 + quad * 8);
  short8 bq1 = *(const short8*)(Qh + (size_t)qrow * 64 + 32 + quad * 8);

  // Staging: lane-linear LDS granules; global side applies the XOR swizzle.
  const int sg = (lane & 7) ^ ((lane >> 3) & 7);  // granule ^ (row&7)
  const int r0 = w * 16 + (lane >> 3);            // row for issue 0 (+8 for issue 1)
  const unsigned short* Kg0 = Kh + r0 * 64 + sg * 8;
  const unsigned short* Vg0 = Vh + (size_t)r0 * SV_ + sg * 8;
  const int lds0 = w * 1024;       // shorts (16 rows x 64), wave-uniform
  const int lds1 = lds0 + 512;     // +8 rows

  auto stage = [&](int kt) {
    const int buf = kt % 3;
    const unsigned short* kg = Kg0 + kt * 4096;
    const unsigned short* vg = Vg0 + kt * 64;
    __builtin_amdgcn_global_load_lds(
        (const __attribute__((address_space(1))) unsigned int*)kg,
        (__attribute__((address_space(3))) unsigned int*)(&Ks[buf][lds0]), 16, 0, 0);
    __builtin_amdgcn_global_load_lds(
        (const __attribute__((address_space(1))) unsigned int*)(kg + 8 * 64),
        (__attribute__((address_space(3))) unsigned int*)(&Ks[buf][lds1]), 16, 0, 0);
    __builtin_amdgcn_global_load_lds(
        (const __attribute__((address_space(1))) unsigned int*)vg,
        (__attribute__((address_space(3))) unsigned int*)(&Vs[buf][lds0]), 16, 0, 0);
    __builtin_amdgcn_global_load_lds(
        (const __attribute__((address_space(1))) unsigned int*)(vg + (size_t)8 * SV_),
        (__attribute__((address_space(3))) unsigned int*)(&Vs[buf][lds1]), 16, 0, 0);
  };

  float l_sum = 0.f;
  f32x4 o_acc[4];
#pragma unroll
  for (int nd = 0; nd < 4; ++nd) o_acc[nd] = (f32x4){0.f, 0.f, 0.f, 0.f};

  const int nt = qt + 1;
  stage(0);
  if (nt > 1) stage(1);

  for (int kt = 0; kt < nt; ++kt) {
    const int buf = kt % 3;
    if (kt + 1 < nt) {
      asm volatile("s_waitcnt vmcnt(4)" ::: "memory");
    } else {
      asm volatile("s_waitcnt vmcnt(0)" ::: "memory");
    }
    asm volatile("s_barrier" ::: "memory");
    if (kt + 2 < nt) stage(kt + 2);   // overwrites buf (kt-1)%3: safe now

    // ---- K fragments from LDS ----
    const unsigned short* Kb = Ks[buf];
    short8 ka[4][2];
#pragma unroll
    for (int t4 = 0; t4 < 4; ++t4)
#pragma unroll
      for (int c = 0; c < 2; ++c)
        ka[t4][c] = *(const short8*)(Kb + (t4 * 16 + lq) * 64 + (((c * 4 + quad) ^ l3) * 8));

    // ---- S^T = K·Q^T (Q pre-scaled by SCALE*log2e) ----
    f32x4 s[4];
#pragma unroll
    for (int t4 = 0; t4 < 4; ++t4) {
      f32x4 z = (f32x4){0.f, 0.f, 0.f, 0.f};
      z = __builtin_amdgcn_mfma_f32_16x16x32_bf16(ka[t4][0], bq0, z, 0, 0, 0);
      s[t4] = __builtin_amdgcn_mfma_f32_16x16x32_bf16(ka[t4][1], bq1, z, 0, 0, 0);
    }

    // ---- p = exp2(s), diagonal mask, in-lane row-sum, in-register PV ----
    const bool diag = (kt == qt);
    const int kc0 = kt * 64 + quad * 4;
    const unsigned short* Vb = Vs[buf];
    float rs = 0.f;
    __builtin_amdgcn_s_setprio(1);
#pragma unroll
    for (int t4 = 0; t4 < 4; ++t4) {
      float p0 = EXP2(s[t4][0]), p1 = EXP2(s[t4][1]);
      float p2 = EXP2(s[t4][2]), p3 = EXP2(s[t4][3]);
      if (diag) {
        const int kc = kc0 + t4 * 16;
        if (kc + 0 > qrow) p0 = 0.f;
        if (kc + 1 > qrow) p1 = 0.f;
        if (kc + 2 > qrow) p2 = 0.f;
        if (kc + 3 > qrow) p3 = 0.f;
      }
      rs += (p0 + p1) + (p2 + p3);
      unsigned ww[2];
      ww[0] = pack_bf2(p0, p1);
      ww[1] = pack_bf2(p2, p3);
      short4b pb;
      __builtin_memcpy(&pb, ww, 8);
      const int cg = t4 * 2 + (quad >> 1);
      const int vcol = ((cg ^ l3) * 8) + (quad & 1) * 4;
#pragma unroll
      for (int nd = 0; nd < 4; ++nd) {
        short4b va4;
        __builtin_memcpy(&va4, Vb + (nd * 16 + lq) * 64 + vcol, 8);
        o_acc[nd] = __builtin_amdgcn_mfma_f32_16x16x16bf16_1k(va4, pb,
                                                              o_acc[nd], 0, 0, 0);
      }
    }
    __builtin_amdgcn_s_setprio(0);
    l_sum += rs;
  }

  // final cross-quad row-sum reduction
  l_sum += __shfl_xor(l_sum, 16);
  l_sum += __shfl_xor(l_sum, 32);

  const int b = bh >> 4, h = bh & 15;
  const float inv = 1.0f / l_sum;
  const int n = qrow >> 1, p = qrow & 1;
  unsigned short* dst = Aov + ((size_t)(b * 1024 + n)) * 2048 + (h * 2 + p) * 64;
#pragma unroll
  for (int nd = 0; nd < 4; ++nd) {
    uint2 dw;
    dw.x = pack_bf2(o_acc[nd][0] * inv, o_acc[nd][1] * inv);
    dw.y = pack_bf2(o_acc[nd][2] * inv, o_acc[nd][3] * inv);
    *(uint2*)(dst + nd * 16 + quad * 4) = dw;
  }
}

// ---------------------------------------------------------------------------
extern "C" void kernel_launch(void* const* d_in, const int* in_sizes, int n_in,
                              void* d_out, int out_size, void* d_ws, size_t ws_size,
                              hipStream_t stream) {
  (void)in_sizes; (void)n_in; (void)out_size; (void)ws_size;
  const float* x    = (const float*)d_in[0];
  const float* Wq   = (const float*)d_in[1];
  const float* Wk   = (const float*)d_in[2];
  const float* Wv   = (const float*)d_in[3];
  const float* Wo   = (const float*)d_in[4];
  const float* aq   = (const float*)d_in[5];
  const float* ak   = (const float*)d_in[6];
  const float* av   = (const float*)d_in[7];
  const float* coll = (const float*)d_in[8];
  float* out = (float*)d_out;

  char* ws = (char*)d_ws;
  const size_t MB = 1024 * 1024;
  unsigned short* Xb    = (unsigned short*)(ws);            // 4 MB  [0,4)
  unsigned short* Woeff = (unsigned short*)(ws + 4 * MB);   // 4 MB  [4,8)
  unsigned short* Weff  = (unsigned short*)(ws + 8 * MB);   // 12 MB [8,20)
  unsigned short* Qv    = (unsigned short*)(ws + 20 * MB);  // 8 MB  [20,28)
  unsigned short* Kv    = (unsigned short*)(ws + 28 * MB);  // 8 MB  [28,36)
  unsigned short* Vt    = (unsigned short*)(ws + 36 * MB);  // 8 MB  [36,44)
  // Weff dead after QKV GEMM; reuse:
  unsigned short* Aov   = (unsigned short*)(ws + 8 * MB);   // 8 MB  [8,16)

  cast_f32_bf16<<<dim3(1024), dim3(256), 0, stream>>>(x, Xb, (B_ * S_ * HID_) / 4);
  weff_kernel<<<dim3(64, 3), dim3(256), 0, stream>>>(Wq, Wk, Wv, aq, ak, av, Weff);
  qkv_gemm128<<<dim3(16, 16, 3), dim3(256), 0, stream>>>(Xb, Weff, Qv, Kv, Vt);
  attn_kernel<<<dim3(32, 32), dim3(256), 0, stream>>>(Qv, Kv, Vt, Aov);
  woeff_kernel<<<dim3(1024), dim3(256), 0, stream>>>(Wo, coll, Woeff);
  gemm64p<<<dim3(32, 16), dim3(256), 0, stream>>>(Aov, Woeff, out);
}

// Round 11
// 189.062 us; speedup vs baseline: 1.3901x; 1.0077x over previous
//
#include <hip/hip_runtime.h>
#include <hip/hip_bf16.h>

// Problem constants
#define B_    2
#define S_    1024
#define HID_  1024
#define H_    16
#define P_    2
#define D_    64
#define SV_   2048   // S_*P_
#define NBH_  32     // B_*H_
// SCALE * log2(e) = 0.125 * 1.4426950408889634
#define SCALE_LOG2E 0.18033688f

typedef __attribute__((ext_vector_type(8))) short short8;
typedef __attribute__((ext_vector_type(4))) short short4b;
typedef __attribute__((ext_vector_type(4))) float f32x4;

#if __has_builtin(__builtin_amdgcn_exp2f)
#define EXP2(x) __builtin_amdgcn_exp2f(x)
#else
#define EXP2(x) exp2f(x)
#endif

__device__ __forceinline__ unsigned short f2bf(float f) {
  union { float f; unsigned u; } v; v.f = f;
  unsigned r = v.u + 0x7fffu + ((v.u >> 16) & 1u);
  return (unsigned short)(r >> 16);
}
__device__ __forceinline__ unsigned pack_bf2(float a, float b) {
  __hip_bfloat162 h = __float22bfloat162_rn(make_float2(a, b));
  unsigned u; __builtin_memcpy(&u, &h, 4);
  return u;
}

// ---------------------------------------------------------------------------
// Fused prep kernel: 3 independent small kernels in ONE launch (saves 2
// launch/drain gaps; overlaps memory-bound cast with VALU-bound weight prep).
//   blocks [0,1024):    cast x f32 -> Xb bf16 (grid-stride over 524288 f32x4)
//   blocks [1024,1216):  weff  (d = b%64, t = b/64)
//   blocks [1216,2240):  woeff (f = b-1216)
__global__ __launch_bounds__(256) void prep_kernel(
    const float* __restrict__ x,
    const float* __restrict__ Wq, const float* __restrict__ Wk,
    const float* __restrict__ Wv, const float* __restrict__ Wo,
    const float* __restrict__ aq, const float* __restrict__ ak,
    const float* __restrict__ av, const float* __restrict__ coll,
    unsigned short* __restrict__ Xb, unsigned short* __restrict__ Weff,
    unsigned short* __restrict__ Woeff) {
  __shared__ float shbuf[1536];   // weff: 512 floats; woeff: 1024+512 floats
  const int bid = blockIdx.x;
  const int tid = threadIdx.x;

  if (bid < 1024) {
    // ---- cast_f32_bf16 ----
    const int n4 = (B_ * S_ * HID_) / 4;
    int i = bid * 256 + tid;
    const int stride = 1024 * 256;
    for (; i < n4; i += stride) {
      float4 v = ((const float4*)x)[i];
      ushort4 o;
      o.x = f2bf(v.x); o.y = f2bf(v.y); o.z = f2bf(v.z); o.w = f2bf(v.w);
      ((ushort4*)Xb)[i] = o;
    }
  } else if (bid < 1216) {
    // ---- weff ----
    const int wb = bid - 1024;
    const int d = wb & 63;        // 0..63
    const int t = wb >> 6;        // 0..2
    const float* W = (t == 0) ? Wq : ((t == 1) ? Wk : Wv);
    const float* A = (t == 0) ? aq : ((t == 1) ? ak : av);
    float (*Al)[32] = (float (*)[32])shbuf;   // [16][32]
    for (int idx = tid; idx < 512; idx += 256) Al[idx >> 5][idx & 31] = A[idx];
    __syncthreads();
    const int e = tid * 4;
    float wr[16][4];
#pragma unroll
    for (int m = 0; m < 16; ++m) {
      float4 v = *(const float4*)(W + (size_t)(m * 64 + d) * 1024 + e);
      wr[m][0] = v.x; wr[m][1] = v.y; wr[m][2] = v.z; wr[m][3] = v.w;
    }
    for (int hp = 0; hp < 32; ++hp) {
      float acc0 = 0.f, acc1 = 0.f, acc2 = 0.f, acc3 = 0.f;
#pragma unroll
      for (int m = 0; m < 16; ++m) {
        float al = Al[m][hp];
        acc0 += al * wr[m][0]; acc1 += al * wr[m][1];
        acc2 += al * wr[m][2]; acc3 += al * wr[m][3];
      }
      int r = (hp >> 1) * 128 + (hp & 1) * 64 + d;
      ushort4 ov;
      ov.x = f2bf(acc0); ov.y = f2bf(acc1); ov.z = f2bf(acc2); ov.w = f2bf(acc3);
      *(ushort4*)(Weff + ((size_t)t * 2048 + r) * 1024 + e) = ov;
    }
  } else {
    // ---- woeff ----
    const int f = bid - 1216;
    float* wrow = shbuf;          // [1024]
    float* cl = shbuf + 1024;     // [512]
    for (int idx = tid; idx < 512; idx += 256) cl[idx] = coll[idx];
    for (int idx = tid; idx < 1024; idx += 256) wrow[idx] = Wo[(size_t)f * 1024 + idx];
    __syncthreads();
    for (int idx = tid; idx < 2048; idx += 256) {
      int o = idx >> 6, d = idx & 63;
      float acc = 0.f;
#pragma unroll
      for (int h = 0; h < 16; ++h) acc += wrow[h * 64 + d] * cl[h * 32 + o];
      Woeff[(size_t)f * 2048 + idx] = f2bf(acc);
    }
  }
}

// ---------------------------------------------------------------------------
// Unified QKV GEMM v2 — 128x128 tile, BK=32, TRIPLE-buffered (48 KB LDS ->
// 3 blocks/CU), ONE barrier + ONE counted vmcnt(4) per K-tile, depth-2
// prefetch. Grid (16,16,3) = 768 blocks = 3/CU.
// z=0: Q = Xb·Weff_q^T (pre-scaled by SCALE_LOG2E); z=1: K; z=2: V^T.
__global__ __launch_bounds__(256, 3) void qkv_gemm128(
    const unsigned short* __restrict__ Xb,
    const unsigned short* __restrict__ Weff,
    unsigned short* __restrict__ Qd, unsigned short* __restrict__ Kd,
    unsigned short* __restrict__ Vd) {
  __shared__ unsigned short As[3][128 * 32];   // 24 KB
  __shared__ unsigned short Bs[3][128 * 32];   // 24 KB
  constexpr int K = 1024, NT = 32;              // K / 32
  const int t = threadIdx.x;
  const int wave = t >> 6, lane = t & 63, lq = lane & 15, quad = lane >> 4;
  const int wm = wave >> 1, wn = wave & 1;      // 2x2 waves, 64x64 each
  const int z = blockIdx.z;
  const int row0 = blockIdx.x * 128, col0 = blockIdx.y * 128;
  const unsigned short* Ap = (z == 2) ? (Weff + (size_t)2 * 2048 * 1024) : Xb;
  const unsigned short* Bp = (z == 2) ? Xb : (Weff + (size_t)z * 2048 * 1024);

  const int srow = lane >> 2;                       // 0..15
  const int sgr = (lane & 3) ^ ((lane >> 3) & 3);   // pre-swizzled granule

  auto stage = [&](int kt, int buf) {
#pragma unroll
    for (int j = 0; j < 2; ++j) {
      const int rloc = wave * 32 + j * 16;  // wave-uniform chunk base row
      const unsigned short* ga =
          Ap + (size_t)(row0 + rloc + srow) * K + kt * 32 + sgr * 8;
      __builtin_amdgcn_global_load_lds(
          (const __attribute__((address_space(1))) unsigned int*)ga,
          (__attribute__((address_space(3))) unsigned int*)(&As[buf][rloc * 32]),
          16, 0, 0);
      const unsigned short* gb =
          Bp + (size_t)(col0 + rloc + srow) * K + kt * 32 + sgr * 8;
      __builtin_amdgcn_global_load_lds(
          (const __attribute__((address_space(1))) unsigned int*)gb,
          (__attribute__((address_space(3))) unsigned int*)(&Bs[buf][rloc * 32]),
          16, 0, 0);
    }
  };

  f32x4 acc[4][4];
#pragma unroll
  for (int mi = 0; mi < 4; ++mi)
#pragma unroll
    for (int ni = 0; ni < 4; ++ni) acc[mi][ni] = (f32x4){0.f, 0.f, 0.f, 0.f};

  stage(0, 0);
  stage(1, 1);

  const int swz4 = (lq >> 1) & 3;   // read-side granule XOR

  for (int kt = 0; kt < NT; ++kt) {
    const int buf = kt % 3;
    if (kt + 1 < NT) {
      asm volatile("s_waitcnt vmcnt(4)" ::: "memory");
    } else {
      asm volatile("s_waitcnt vmcnt(0)" ::: "memory");
    }
    asm volatile("s_barrier" ::: "memory");
    if (kt + 2 < NT) stage(kt + 2, (kt + 2) % 3);  // overwrites (kt-1)%3

    const unsigned short* __restrict__ Ab = &As[buf][0];
    const unsigned short* __restrict__ Bb = &Bs[buf][0];
    short8 af[4], bf[4];
#pragma unroll
    for (int mi = 0; mi < 4; ++mi)
      af[mi] = *(const short8*)(
          Ab + (wm * 64 + mi * 16 + lq) * 32 + ((quad ^ swz4) * 8));
#pragma unroll
    for (int ni = 0; ni < 4; ++ni)
      bf[ni] = *(const short8*)(
          Bb + (wn * 64 + ni * 16 + lq) * 32 + ((quad ^ swz4) * 8));
    __builtin_amdgcn_s_setprio(1);
#pragma unroll
    for (int mi = 0; mi < 4; ++mi)
#pragma unroll
      for (int ni = 0; ni < 4; ++ni)
        acc[mi][ni] = __builtin_amdgcn_mfma_f32_16x16x32_bf16(
            af[mi], bf[ni], acc[mi][ni], 0, 0, 0);
    __builtin_amdgcn_s_setprio(0);
  }

  // Epilogue: scattered bf16 stores into head-interleaved layouts.
#pragma unroll
  for (int mi = 0; mi < 4; ++mi) {
#pragma unroll
    for (int ni = 0; ni < 4; ++ni) {
#pragma unroll
      for (int i = 0; i < 4; ++i) {
        int grow = row0 + wm * 64 + mi * 16 + quad * 4 + i;
        int gcol = col0 + wn * 64 + ni * 16 + lq;
        float val = acc[mi][ni][i];
        if (z != 2) {
          if (z == 0) val *= SCALE_LOG2E;  // pre-scale Q for exp2-direct attn
          int b = grow >> 10, n = grow & 1023;
          int h = gcol >> 7, p = (gcol >> 6) & 1, d = gcol & 63;
          unsigned short* dst = (z == 0) ? Qd : Kd;
          dst[((size_t)((b * 16 + h) * 2048) + n * 2 + p) * 64 + d] = f2bf(val);
        } else {
          // grow = (h,p,d), gcol = (b, n)
          int h = grow >> 7, p = (grow >> 6) & 1, d = grow & 63;
          int b = gcol >> 10, n = gcol & 1023;
          Vd[((size_t)((b * 16 + h) * 64 + d)) * 2048 + n * 2 + p] = f2bf(val);
        }
      }
    }
  }
}

// ---------------------------------------------------------------------------
// Output GEMM, depth-2 pipeline: 64x64 tile, BK=64, TRIPLE-buffered A/B,
// ONE barrier + counted vmcnt(4) per K-tile. Grid (32,16) = 2 blocks/CU.
__global__ __launch_bounds__(256) void gemm64p(
    const unsigned short* __restrict__ A,      // [2048 x 2048] row-major
    const unsigned short* __restrict__ Bbase,  // [1024 x 2048] (B^T form)
    float* __restrict__ Cf) {                  // [2048 x 1024]
  __shared__ unsigned short As[3][64 * 64];    // 24 KB
  __shared__ unsigned short Bs[3][64 * 64];    // 24 KB
  constexpr int K = 2048, N = 1024, NT = 32;   // K / 64
  const int t = threadIdx.x;
  const int wave = t >> 6, lane = t & 63, lrow = lane & 15, quad = lane >> 4;
  const int wm = wave >> 1, wn = wave & 1;     // 2x2 wave grid, 32x32 each
  const int row0 = blockIdx.x * 64, col0 = blockIdx.y * 64;
  const int srow8 = lane >> 3;
  const int sslot = (lane & 7) ^ srow8;        // pre-swizzled global slot
  const int swz = lrow & 7;

  auto stage = [&](int kt, int buf) {
#pragma unroll
    for (int j = 0; j < 2; ++j) {
      const int rloc = wave * 16 + j * 8;
      const unsigned short* ga =
          A + (size_t)(row0 + rloc + srow8) * K + kt * 64 + sslot * 8;
      __builtin_amdgcn_global_load_lds(
          (const __attribute__((address_space(1))) unsigned int*)ga,
          (__attribute__((address_space(3))) unsigned int*)(&As[buf][rloc * 64]),
          16, 0, 0);
      const unsigned short* gb =
          Bbase + (size_t)(col0 + rloc + srow8) * K + kt * 64 + sslot * 8;
      __builtin_amdgcn_global_load_lds(
          (const __attribute__((address_space(1))) unsigned int*)gb,
          (__attribute__((address_space(3))) unsigned int*)(&Bs[buf][rloc * 64]),
          16, 0, 0);
    }
  };

  f32x4 acc[2][2];
#pragma unroll
  for (int mi = 0; mi < 2; ++mi)
#pragma unroll
    for (int ni = 0; ni < 2; ++ni) acc[mi][ni] = (f32x4){0.f, 0.f, 0.f, 0.f};

  stage(0, 0);
  stage(1, 1);

  for (int kt = 0; kt < NT; ++kt) {
    const int buf = kt % 3;
    if (kt < NT - 1) {
      asm volatile("s_waitcnt vmcnt(4)" ::: "memory");  // tile kt landed
    } else {
      asm volatile("s_waitcnt vmcnt(0)" ::: "memory");
    }
    asm volatile("s_barrier" ::: "memory");
    if (kt + 2 < NT) stage(kt + 2, (kt + 2) % 3);

    const unsigned short* __restrict__ Ab = &As[buf][0];
    const unsigned short* __restrict__ Bb = &Bs[buf][0];
    short8 af[2][2], bf[2][2];
#pragma unroll
    for (int mi = 0; mi < 2; ++mi)
#pragma unroll
      for (int ks = 0; ks < 2; ++ks)
        af[mi][ks] = *(const short8*)(
            Ab + (wm * 32 + mi * 16 + lrow) * 64 + (((ks * 4 + quad) ^ swz) * 8));
#pragma unroll
    for (int ni = 0; ni < 2; ++ni)
#pragma unroll
      for (int ks = 0; ks < 2; ++ks)
        bf[ni][ks] = *(const short8*)(
            Bb + (wn * 32 + ni * 16 + lrow) * 64 + (((ks * 4 + quad) ^ swz) * 8));
    __builtin_amdgcn_s_setprio(1);
#pragma unroll
    for (int mi = 0; mi < 2; ++mi)
#pragma unroll
      for (int ni = 0; ni < 2; ++ni) {
        acc[mi][ni] = __builtin_amdgcn_mfma_f32_16x16x32_bf16(
            af[mi][0], bf[ni][0], acc[mi][ni], 0, 0, 0);
        acc[mi][ni] = __builtin_amdgcn_mfma_f32_16x16x32_bf16(
            af[mi][1], bf[ni][1], acc[mi][ni], 0, 0, 0);
      }
    __builtin_amdgcn_s_setprio(0);
  }

#pragma unroll
  for (int mi = 0; mi < 2; ++mi)
#pragma unroll
    for (int ni = 0; ni < 2; ++ni)
#pragma unroll
      for (int i = 0; i < 4; ++i) {
        int grow = row0 + wm * 32 + mi * 16 + quad * 4 + i;
        int gcol = col0 + wn * 32 + ni * 16 + lrow;
        Cf[(size_t)grow * N + gcol] = acc[mi][ni][i];
      }
}

// ---------------------------------------------------------------------------
// Causal flash attention v6: global_load_lds staging, KVBLK=64,
// TRIPLE-buffered K/V (48 KB -> 3 blocks/CU), ONE barrier + ONE counted
// vmcnt per tile, in-register P via 16x16x16 MFMA, Q pre-scaled.
__global__ __launch_bounds__(256, 3) void attn_kernel(
    const unsigned short* __restrict__ Qv, const unsigned short* __restrict__ Kv,
    const unsigned short* __restrict__ Vt, unsigned short* __restrict__ Aov) {
  __shared__ unsigned short Ks[3][4096];   // [buf][row 64][col 64] swizzled
  __shared__ unsigned short Vs[3][4096];   // [buf][d 64][kcol 64] swizzled
  const int bh = blockIdx.x;
  const int yy = blockIdx.y;
  const int qt = (yy < 16) ? yy : (47 - yy);
  const int t = threadIdx.x;
  const int w = t >> 6, lane = t & 63, lq = lane & 15, quad = lane >> 4;
  const int l3 = lq & 7;

  const unsigned short* Qh = Qv + (size_t)bh * SV_ * D_;
  const unsigned short* Kh = Kv + (size_t)bh * SV_ * D_;
  const unsigned short* Vh = Vt + (size_t)bh * D_ * SV_;

  const int qrow = qt * 64 + w * 16 + lq;  // this lane's q row
  short8 bq0 = *(const short8*)(Qh + (size_t)qrow * 64 + quad * 8);
  short8 bq1 = *(const short8*)(Qh + (size_t)qrow * 64 + 32 + quad * 8);

  // Staging: lane-linear LDS granules; global side applies the XOR swizzle.
  const int sg = (lane & 7) ^ ((lane >> 3) & 7);  // granule ^ (row&7)
  const int r0 = w * 16 + (lane >> 3);            // row for issue 0 (+8 for issue 1)
  const unsigned short* Kg0 = Kh + r0 * 64 + sg * 8;
  const unsigned short* Vg0 = Vh + (size_t)r0 * SV_ + sg * 8;
  const int lds0 = w * 1024;       // shorts (16 rows x 64), wave-uniform
  const int lds1 = lds0 + 512;     // +8 rows

  auto stage = [&](int kt) {
    const int buf = kt % 3;
    const unsigned short* kg = Kg0 + kt * 4096;
    const unsigned short* vg = Vg0 + kt * 64;
    __builtin_amdgcn_global_load_lds(
        (const __attribute__((address_space(1))) unsigned int*)kg,
        (__attribute__((address_space(3))) unsigned int*)(&Ks[buf][lds0]), 16, 0, 0);
    __builtin_amdgcn_global_load_lds(
        (const __attribute__((address_space(1))) unsigned int*)(kg + 8 * 64),
        (__attribute__((address_space(3))) unsigned int*)(&Ks[buf][lds1]), 16, 0, 0);
    __builtin_amdgcn_global_load_lds(
        (const __attribute__((address_space(1))) unsigned int*)vg,
        (__attribute__((address_space(3))) unsigned int*)(&Vs[buf][lds0]), 16, 0, 0);
    __builtin_amdgcn_global_load_lds(
        (const __attribute__((address_space(1))) unsigned int*)(vg + (size_t)8 * SV_),
        (__attribute__((address_space(3))) unsigned int*)(&Vs[buf][lds1]), 16, 0, 0);
  };

  float l_sum = 0.f;
  f32x4 o_acc[4];
#pragma unroll
  for (int nd = 0; nd < 4; ++nd) o_acc[nd] = (f32x4){0.f, 0.f, 0.f, 0.f};

  const int nt = qt + 1;
  stage(0);
  if (nt > 1) stage(1);

  for (int kt = 0; kt < nt; ++kt) {
    const int buf = kt % 3;
    if (kt + 1 < nt) {
      asm volatile("s_waitcnt vmcnt(4)" ::: "memory");
    } else {
      asm volatile("s_waitcnt vmcnt(0)" ::: "memory");
    }
    asm volatile("s_barrier" ::: "memory");
    if (kt + 2 < nt) stage(kt + 2);   // overwrites buf (kt-1)%3: safe now

    // ---- K fragments from LDS ----
    const unsigned short* Kb = Ks[buf];
    short8 ka[4][2];
#pragma unroll
    for (int t4 = 0; t4 < 4; ++t4)
#pragma unroll
      for (int c = 0; c < 2; ++c)
        ka[t4][c] = *(const short8*)(Kb + (t4 * 16 + lq) * 64 + (((c * 4 + quad) ^ l3) * 8));

    // ---- S^T = K·Q^T (Q pre-scaled by SCALE*log2e) ----
    f32x4 s[4];
#pragma unroll
    for (int t4 = 0; t4 < 4; ++t4) {
      f32x4 z = (f32x4){0.f, 0.f, 0.f, 0.f};
      z = __builtin_amdgcn_mfma_f32_16x16x32_bf16(ka[t4][0], bq0, z, 0, 0, 0);
      s[t4] = __builtin_amdgcn_mfma_f32_16x16x32_bf16(ka[t4][1], bq1, z, 0, 0, 0);
    }

    // ---- p = exp2(s), diagonal mask, in-lane row-sum, in-register PV ----
    const bool diag = (kt == qt);
    const int kc0 = kt * 64 + quad * 4;
    const unsigned short* Vb = Vs[buf];
    float rs = 0.f;
    __builtin_amdgcn_s_setprio(1);
#pragma unroll
    for (int t4 = 0; t4 < 4; ++t4) {
      float p0 = EXP2(s[t4][0]), p1 = EXP2(s[t4][1]);
      float p2 = EXP2(s[t4][2]), p3 = EXP2(s[t4][3]);
      if (diag) {
        const int kc = kc0 + t4 * 16;
        if (kc + 0 > qrow) p0 = 0.f;
        if (kc + 1 > qrow) p1 = 0.f;
        if (kc + 2 > qrow) p2 = 0.f;
        if (kc + 3 > qrow) p3 = 0.f;
      }
      rs += (p0 + p1) + (p2 + p3);
      unsigned ww[2];
      ww[0] = pack_bf2(p0, p1);
      ww[1] = pack_bf2(p2, p3);
      short4b pb;
      __builtin_memcpy(&pb, ww, 8);
      const int cg = t4 * 2 + (quad >> 1);
      const int vcol = ((cg ^ l3) * 8) + (quad & 1) * 4;
#pragma unroll
      for (int nd = 0; nd < 4; ++nd) {
        short4b va4;
        __builtin_memcpy(&va4, Vb + (nd * 16 + lq) * 64 + vcol, 8);
        o_acc[nd] = __builtin_amdgcn_mfma_f32_16x16x16bf16_1k(va4, pb,
                                                              o_acc[nd], 0, 0, 0);
      }
    }
    __builtin_amdgcn_s_setprio(0);
    l_sum += rs;
  }

  // final cross-quad row-sum reduction
  l_sum += __shfl_xor(l_sum, 16);
  l_sum += __shfl_xor(l_sum, 32);

  const int b = bh >> 4, h = bh & 15;
  const float inv = 1.0f / l_sum;
  const int n = qrow >> 1, p = qrow & 1;
  unsigned short* dst = Aov + ((size_t)(b * 1024 + n)) * 2048 + (h * 2 + p) * 64;
#pragma unroll
  for (int nd = 0; nd < 4; ++nd) {
    uint2 dw;
    dw.x = pack_bf2(o_acc[nd][0] * inv, o_acc[nd][1] * inv);
    dw.y = pack_bf2(o_acc[nd][2] * inv, o_acc[nd][3] * inv);
    *(uint2*)(dst + nd * 16 + quad * 4) = dw;
  }
}

// ---------------------------------------------------------------------------
extern "C" void kernel_launch(void* const* d_in, const int* in_sizes, int n_in,
                              void* d_out, int out_size, void* d_ws, size_t ws_size,
                              hipStream_t stream) {
  (void)in_sizes; (void)n_in; (void)out_size; (void)ws_size;
  const float* x    = (const float*)d_in[0];
  const float* Wq   = (const float*)d_in[1];
  const float* Wk   = (const float*)d_in[2];
  const float* Wv   = (const float*)d_in[3];
  const float* Wo   = (const float*)d_in[4];
  const float* aq   = (const float*)d_in[5];
  const float* ak   = (const float*)d_in[6];
  const float* av   = (const float*)d_in[7];
  const float* coll = (const float*)d_in[8];
  float* out = (float*)d_out;

  char* ws = (char*)d_ws;
  const size_t MB = 1024 * 1024;
  unsigned short* Xb    = (unsigned short*)(ws);            // 4 MB  [0,4)
  unsigned short* Woeff = (unsigned short*)(ws + 4 * MB);   // 4 MB  [4,8)
  unsigned short* Weff  = (unsigned short*)(ws + 8 * MB);   // 12 MB [8,20)
  unsigned short* Qv    = (unsigned short*)(ws + 20 * MB);  // 8 MB  [20,28)
  unsigned short* Kv    = (unsigned short*)(ws + 28 * MB);  // 8 MB  [28,36)
  unsigned short* Vt    = (unsigned short*)(ws + 36 * MB);  // 8 MB  [36,44)
  // Weff dead after QKV GEMM; reuse:
  unsigned short* Aov   = (unsigned short*)(ws + 8 * MB);   // 8 MB  [8,16)

  prep_kernel<<<dim3(2240), dim3(256), 0, stream>>>(
      x, Wq, Wk, Wv, Wo, aq, ak, av, coll, Xb, Weff, Woeff);
  qkv_gemm128<<<dim3(16, 16, 3), dim3(256), 0, stream>>>(Xb, Weff, Qv, Kv, Vt);
  attn_kernel<<<dim3(32, 32), dim3(256), 0, stream>>>(Qv, Kv, Vt, Aov);
  gemm64p<<<dim3(32, 16), dim3(256), 0, stream>>>(Aov, Woeff, out);
}